// Round 8
// baseline (433.691 us; speedup 1.0000x reference)
//
#include <hip/hip_runtime.h>
#include <math.h>

#define B_ 4
#define L_ 2048
#define DM 1024
#define H_ 16
#define HD_ 64
#define NH_ 64            // B_*H_
#define EPS_ 1e-6f

typedef float f32x4 __attribute__((ext_vector_type(4)));
typedef short short8 __attribute__((ext_vector_type(8)));

typedef __attribute__((address_space(3))) void lds_v;
typedef const __attribute__((address_space(1))) void glb_v;
#define GLOAD16(g, l) __builtin_amdgcn_global_load_lds((glb_v*)(g), (lds_v*)(l), 16, 0, 0)

#define SCHED0() __builtin_amdgcn_sched_barrier(0)
#define SBAR() do { SCHED0(); __builtin_amdgcn_s_barrier(); SCHED0(); } while (0)
#define WAITV(N) do { SCHED0(); asm volatile("s_waitcnt vmcnt(" #N ")" ::: "memory"); SCHED0(); } while (0)
#define LGKM0() do { asm volatile("s_waitcnt lgkmcnt(0)" ::: "memory"); SCHED0(); } while (0)

__device__ __forceinline__ float sigmoidf_(float x) { return 1.0f / (1.0f + expf(-x)); }

// round-to-nearest-even f32 -> bf16 bits
__device__ __forceinline__ short f2bf(float x) {
    unsigned u = __float_as_uint(x);
    unsigned r = (u + 0x7FFFu + ((u >> 16) & 1u)) >> 16;
    return (short)r;
}
__device__ __forceinline__ float bf2f(short h) {
    return __uint_as_float(((unsigned)(unsigned short)h) << 16);
}

__global__ __launch_bounds__(256) void zero_kernel(float* __restrict__ p, int n)
{
    const int i = blockIdx.x * 256 + threadIdx.x;
    if (i < n) p[i] = 0.f;
}

// ---------------------------------------------------------------------------
// Split f32 array into bf16 hi/lo (x = hi + lo to ~2^-17 relative).
// ---------------------------------------------------------------------------
__global__ __launch_bounds__(256) void split_kernel(
    const float* __restrict__ in, short* __restrict__ hi, short* __restrict__ lo, int n4)
{
    const int i = blockIdx.x * 256 + threadIdx.x;
    if (i >= n4) return;
    f32x4 v = *(const f32x4*)(in + (size_t)i * 4);
    short h[4], l[4];
    #pragma unroll
    for (int j = 0; j < 4; ++j) {
        h[j] = f2bf(v[j]);
        l[j] = f2bf(v[j] - bf2f(h[j]));
    }
    typedef short short4_ __attribute__((ext_vector_type(4)));
    *(short4_*)(hi + (size_t)i * 4) = short4_{h[0], h[1], h[2], h[3]};
    *(short4_*)(lo + (size_t)i * 4) = short4_{l[0], l[1], l[2], l[3]};
}

// all 4 weight splits in one launch (blockIdx.y selects the matrix)
__global__ __launch_bounds__(256) void split_w4_kernel(
    const float* __restrict__ Wq, const float* __restrict__ Wk,
    const float* __restrict__ Wv, const float* __restrict__ Wo,
    short* __restrict__ wh3, short* __restrict__ wl3,
    short* __restrict__ woh, short* __restrict__ wol)
{
    const int y = blockIdx.y;
    const float* src = (y == 0) ? Wq : (y == 1) ? Wk : (y == 2) ? Wv : Wo;
    short* hh = (y < 3) ? (wh3 + (size_t)y * DM * DM) : woh;
    short* ll = (y < 3) ? (wl3 + (size_t)y * DM * DM) : wol;
    const int i = blockIdx.x * 256 + threadIdx.x;   // i < DM*DM/4
    f32x4 v = *(const f32x4*)(src + (size_t)i * 4);
    short h[4], l[4];
    #pragma unroll
    for (int j = 0; j < 4; ++j) {
        h[j] = f2bf(v[j]);
        l[j] = f2bf(v[j] - bf2f(h[j]));
    }
    typedef short short4_ __attribute__((ext_vector_type(4)));
    *(short4_*)(hh + (size_t)i * 4) = short4_{h[0], h[1], h[2], h[3]};
    *(short4_*)(ll + (size_t)i * 4) = short4_{l[0], l[1], l[2], l[3]};
}

// ===========================================================================
// 8-phase 256x256 split-bf16 MFMA GEMM (m201-template port), qkv only.
//   K' = 3*1024 = 48 K-tiles of 64; tile t = (c3, prod): A = prod<2?Ah:Al,
//   B = prod==1?Bl:Bh.  8 waves (2M x 4N), per-wave C = 128x64 (8x4 frags).
//   LDS 128 KB: 2 dbuf x {A-ks0,A-ks1,B-ks0,B-ks1} 16 KB slabs ([256r][32k]).
//   Iteration = 2 K-tiles = 8 phases; phase (d,ks,mh):
//     ds_read B[4] (if mh==0) + A[4]; stage half (ph+6); vmcnt(6) counted
//     (vmcnt(0) once staging ends); barrier; lgkmcnt(0); setprio; 16 MFMA;
//     setprio; barrier.
//   Schedule verified: every half is read >=5 phases after its stage (vmcnt(6)
//   retires >=4-back); every region re-staged exactly 1+ barrier after its
//   last read.  Swizzle slot' = kc ^ ((row>>1)&3) on 16B slots of 64B rows
//   (2-way, free); linear gload dest + inverse-swizzled source k-offset.
// ===========================================================================
__global__ __launch_bounds__(512, 2) void gemm_qkv8_kernel(
    const short* __restrict__ Ah, const short* __restrict__ Al,
    const short* __restrict__ wh, const short* __restrict__ wl,   // [3][DM][DM]
    const float* __restrict__ bq, const float* __restrict__ bk, const float* __restrict__ bv,
    float* __restrict__ qb, float* __restrict__ kb, float* __restrict__ vb,
    float* __restrict__ qsum, float* __restrict__ ksum)
{
    __shared__ char lds[131072];
    const int wg = ((int)blockIdx.x & 7) * 48 + ((int)blockIdx.x >> 3);  // XCD (384%8==0)
    const int by = wg & 31;
    const int bx = wg >> 5;          // 0..11
    const int row0 = by * 256;
    const int col0 = bx * 256;       // [0,3072)
    const int z = bx >> 2;
    const short* Bh = wh;            // packed: col0 indexes into [3][DM][DM] rows
    const short* Bl = wl;

    const int tid = threadIdx.x;
    const int lane = tid & 63;
    const int fr = lane & 15;
    const int kc = lane >> 4;                 // 0..3
    const int w  = tid >> 6;
    const int wm = w >> 2;                    // 0..1
    const int wn = w & 3;                     // 0..3
    const int swz = ((kc ^ ((fr >> 1) & 3)) << 4);              // read swizzle bytes
    const int srck = (((tid & 3) ^ ((tid >> 3) & 3)) << 3);     // stage source k-elems
    const int strow = tid >> 2;               // stage row for j=0 (j=1: +128)
    const int stlb = tid * 16;

    f32x4 acc[8][4];
    #pragma unroll
    for (int m = 0; m < 8; ++m)
        #pragma unroll
        for (int n = 0; n < 4; ++n) acc[m][n] = f32x4{0.f, 0.f, 0.f, 0.f};

    // stage half hs: tile = hs>>2; slot: 0=A-ks0 1=B-ks0 2=A-ks1 3=B-ks1
    #define STAGE8(hs) do {                                                       \
        const int tile_ = (hs) >> 2, slot_ = (hs) & 3;                            \
        const int c3_ = tile_ / 3, prod_ = tile_ - c3_ * 3;                       \
        const short* s_ = (slot_ & 1) ? ((prod_ == 1) ? Bl : Bh)                  \
                                      : ((prod_ < 2) ? Ah : Al);                  \
        const int r0_ = (slot_ & 1) ? col0 : row0;                                \
        const int kb_ = c3_ * 64 + (slot_ >> 1) * 32 + srck;                      \
        char* dst_ = lds + (tile_ & 1) * 65536 + (slot_ & 1) * 32768              \
                         + (slot_ >> 1) * 16384;                                  \
        GLOAD16(s_ + (size_t)(r0_ + strow) * DM + kb_, dst_ + stlb);              \
        GLOAD16(s_ + (size_t)(r0_ + 128 + strow) * DM + kb_, dst_ + 8192 + stlb); \
    } while (0)

    // prologue: halves 0..5, retire 0,1
    STAGE8(0); STAGE8(1); STAGE8(2); STAGE8(3); STAGE8(4); STAGE8(5);
    WAITV(8);
    SBAR();

    short8 bF[4];
    #define NHALVES_ 192
    for (int it = 0; it < 24; ++it) {
        #pragma unroll
        for (int d = 0; d < 2; ++d) {
            #pragma unroll
            for (int ks = 0; ks < 2; ++ks) {
                const char* As = lds + d * 65536 + ks * 16384;
                const char* Bs = lds + d * 65536 + 32768 + ks * 16384;
                #pragma unroll
                for (int mh = 0; mh < 2; ++mh) {
                    const int ph = it * 8 + d * 4 + ks * 2 + mh;
                    if (mh == 0) {
                        #pragma unroll
                        for (int n = 0; n < 4; ++n) {
                            const int rB = wn * 64 + n * 16 + fr;
                            bF[n] = *(const short8*)(Bs + rB * 64 + swz);
                        }
                    }
                    short8 aF[4];
                    #pragma unroll
                    for (int m2 = 0; m2 < 4; ++m2) {
                        const int rA = wm * 128 + mh * 64 + m2 * 16 + fr;
                        aF[m2] = *(const short8*)(As + rA * 64 + swz);
                    }
                    const int hs = ph + 6;
                    if (hs < NHALVES_) { STAGE8(hs); WAITV(6); }
                    else               { WAITV(0); }
                    SBAR();
                    LGKM0();
                    __builtin_amdgcn_s_setprio(1);
                    #pragma unroll
                    for (int m2 = 0; m2 < 4; ++m2)
                        #pragma unroll
                        for (int n = 0; n < 4; ++n)
                            acc[mh * 4 + m2][n] = __builtin_amdgcn_mfma_f32_16x16x32_bf16(
                                aF[m2], bF[n], acc[mh * 4 + m2][n], 0, 0, 0);
                    __builtin_amdgcn_s_setprio(0);
                    SBAR();
                }
            }
        }
    }
    #undef STAGE8

    // epilogue: +bias, sigmoid q/k, scatter [B,H,L,HD], fused colsum
    const float* __restrict__ bias = (z == 0) ? bq : (z == 1) ? bk : bv;
    float* __restrict__ outp       = (z == 0) ? qb : (z == 1) ? kb : vb;
    float csum[4] = {0.f, 0.f, 0.f, 0.f};
    #pragma unroll
    for (int m = 0; m < 8; ++m) {
        const int gr0 = row0 + wm * 128 + m * 16 + kc * 4;
        #pragma unroll
        for (int n = 0; n < 4; ++n) {
            const int j = (col0 & 1023) + wn * 64 + n * 16 + fr;
            const float bj = bias[j];
            const int h = j >> 6, dd = j & 63;
            #pragma unroll
            for (int r2 = 0; r2 < 4; ++r2) {
                const int i = gr0 + r2;
                const int nn = i >> 11, l = i & (L_ - 1);
                float v = acc[m][n][r2] + bj;
                if (z < 2) { v = sigmoidf_(v); csum[n] += v; }
                outp[(((size_t)(nn * H_ + h)) * L_ + l) * HD_ + dd] = v;
            }
        }
    }
    if (z < 2) {
        float* scol = (float*)lds;             // LDS free after final barrier
        if (tid < 256) scol[tid] = 0.f;
        __syncthreads();
        #pragma unroll
        for (int n = 0; n < 4; ++n)
            atomicAdd(&scol[wn * 64 + n * 16 + fr], csum[n]);
        __syncthreads();
        if (tid < 256) {
            const int j = (col0 & 1023) + tid;
            const int nn = row0 >> 11;
            float* dst = (z == 0) ? qsum : ksum;
            atomicAdd(&dst[(nn * H_ + (j >> 6)) * 64 + (j & 63)], scol[tid]);
        }
    }
}

// ---------------------------------------------------------------------------
// m97-structure GEMM core (proven R2) — used for the output projection.
// ---------------------------------------------------------------------------
__device__ __forceinline__ void gemm_core(
    const short* __restrict__ Ah_g, const short* __restrict__ Al_g,
    const short* __restrict__ Bh_g, const short* __restrict__ Bl_g,
    int row0, int col0, short* lds, f32x4 acc[4][4])
{
    const int t = threadIdx.x;
    const int lane = t & 63;
    const int w = t >> 6;
    const int wr = w >> 1, wc = w & 1;
    const int fr = lane & 15, kc = lane >> 4;

    for (int k0 = 0; k0 < DM; k0 += 32) {
        const short* a_h = Ah_g + (size_t)row0 * DM + k0;
        const short* a_l = Al_g + (size_t)row0 * DM + k0;
        const short* b_h = Bh_g + (size_t)col0 * DM + k0;
        const short* b_l = Bl_g + (size_t)col0 * DM + k0;
        #pragma unroll
        for (int p = 0; p < 2; ++p) {
            const int b = p * 4096 + t * 16;
            const int r = b >> 6;
            const int s = (b >> 4) & 3;
            const int fsw = (r & 3) ^ ((r >> 2) & 3);
            const int c = ((s ^ fsw) << 3);
            const size_t go = (size_t)r * DM + c;
            GLOAD16(a_h + go, lds + 0 * 4096 + (b >> 1));
            GLOAD16(a_l + go, lds + 1 * 4096 + (b >> 1));
            GLOAD16(b_h + go, lds + 2 * 4096 + (b >> 1));
            GLOAD16(b_l + go, lds + 3 * 4096 + (b >> 1));
        }
        __syncthreads();

        short8 bhf[4], blf[4];
        #pragma unroll
        for (int n = 0; n < 4; ++n) {
            const int row = wc * 64 + n * 16 + fr;
            const int fsw = (row & 3) ^ ((row >> 2) & 3);
            const int off = row * 32 + ((kc ^ fsw) << 3);
            bhf[n] = *(const short8*)(lds + 2 * 4096 + off);
            blf[n] = *(const short8*)(lds + 3 * 4096 + off);
        }
        #pragma unroll
        for (int m = 0; m < 4; ++m) {
            const int row = wr * 64 + m * 16 + fr;
            const int fsw = (row & 3) ^ ((row >> 2) & 3);
            const int off = row * 32 + ((kc ^ fsw) << 3);
            short8 ahf = *(const short8*)(lds + 0 * 4096 + off);
            short8 alf = *(const short8*)(lds + 1 * 4096 + off);
            #pragma unroll
            for (int n = 0; n < 4; ++n) {
                acc[m][n] = __builtin_amdgcn_mfma_f32_16x16x32_bf16(ahf, bhf[n], acc[m][n], 0, 0, 0);
                acc[m][n] = __builtin_amdgcn_mfma_f32_16x16x32_bf16(ahf, blf[n], acc[m][n], 0, 0, 0);
                acc[m][n] = __builtin_amdgcn_mfma_f32_16x16x32_bf16(alf, bhf[n], acc[m][n], 0, 0, 0);
            }
        }
        __syncthreads();
    }
}

// Final GEMM: out = attn_hi/lo @ Wo^T + bo, plain [B*L, DM] f32 store.
__global__ __launch_bounds__(256) void gemm_out_kernel(
    const short* __restrict__ ah, const short* __restrict__ al,
    const short* __restrict__ wh, const short* __restrict__ wl,
    const float* __restrict__ bias, float* __restrict__ outp)
{
    __shared__ short lds[4 * 4096];
    const int row0 = blockIdx.y * 128;
    const int col0 = blockIdx.x * 128;
    f32x4 acc[4][4];
    #pragma unroll
    for (int m = 0; m < 4; ++m)
        #pragma unroll
        for (int n = 0; n < 4; ++n) acc[m][n] = f32x4{0.f, 0.f, 0.f, 0.f};

    gemm_core(ah, al, wh, wl, row0, col0, lds, acc);

    const int lane = threadIdx.x & 63;
    const int w = threadIdx.x >> 6;
    const int wr = w >> 1, wc = w & 1;
    const int fr = lane & 15, kc = lane >> 4;
    #pragma unroll
    for (int m = 0; m < 4; ++m) {
        const int gr0 = row0 + wr * 64 + m * 16 + kc * 4;
        #pragma unroll
        for (int n = 0; n < 4; ++n) {
            const int j = col0 + wc * 64 + n * 16 + fr;
            const float bj = bias[j];
            #pragma unroll
            for (int r2 = 0; r2 < 4; ++r2)
                outp[(size_t)(gr0 + r2) * DM + j] = acc[m][n][r2] + bj;
        }
    }
}

// ---------------------------------------------------------------------------
// stage1: per l compute si (stored) and so (inline); atomicAdd qsi/kso.
// ---------------------------------------------------------------------------
__global__ __launch_bounds__(256) void stage1_part_kernel(
    const float* __restrict__ q, const float* __restrict__ k,
    const float* __restrict__ qsum, const float* __restrict__ ksum,
    float* __restrict__ si, float* __restrict__ qsi, float* __restrict__ kso)
{
    const int nh = blockIdx.x, ch = blockIdx.y;
    const float* qp = q + (size_t)nh * L_ * HD_;
    const float* kp = k + (size_t)nh * L_ * HD_;
    const int lane = threadIdx.x & 63;
    const int w = threadIdx.x >> 6;
    const float ksv = ksum[nh * 64 + lane] + EPS_;
    const float qsv = qsum[nh * 64 + lane] + EPS_;
    float qsi_acc = 0.f, kso_acc = 0.f;
    for (int l = ch * 128 + w; l < (ch + 1) * 128; l += 4) {
        const float qv = qp[(size_t)l * HD_ + lane];
        const float kv = kp[(size_t)l * HD_ + lane];
        float a = (qv + EPS_) * ksv;
        float b = (kv + EPS_) * qsv;
        #pragma unroll
        for (int off = 32; off >= 1; off >>= 1) {
            a += __shfl_xor(a, off, 64);
            b += __shfl_xor(b, off, 64);
        }
        const float siv = 1.f / a;
        const float sov = 1.f / b;
        if (lane == 0) si[nh * L_ + l] = siv;
        qsi_acc += qv * siv;
        kso_acc += kv * sov;
    }
    __shared__ float s1[4][64], s2[4][64];
    s1[w][lane] = qsi_acc; s2[w][lane] = kso_acc;
    __syncthreads();
    if (w == 0) {
        atomicAdd(&qsi[nh * 64 + lane], s1[0][lane] + s1[1][lane] + s1[2][lane] + s1[3][lane]);
        atomicAdd(&kso[nh * 64 + lane], s2[0][lane] + s2[1][lane] + s2[2][lane] + s2[3][lane]);
    }
}

// ---------------------------------------------------------------------------
// kv partial over 256-l chunk WITH fused source-competition numerator.
// ---------------------------------------------------------------------------
__global__ __launch_bounds__(256) void kv_part_kernel(
    const float* __restrict__ k, const float* __restrict__ v,
    const float* __restrict__ qsi, float* __restrict__ kvp, float* __restrict__ psum_p)
{
    const int nh = blockIdx.x, ch = blockIdx.y;
    const float* kp = k + (size_t)nh * L_ * HD_;
    const float* vp = v + (size_t)nh * L_ * HD_;
    const int lane = threadIdx.x & 63;
    const int w = threadIdx.x >> 6;
    const float qsiv = qsi[nh * 64 + lane] + EPS_;

    float acc[16] = {0.f};
    float psum = 0.f;
    __shared__ float ks[32][64], vs[32][64];
    __shared__ float pl[32];
    for (int l0 = ch * 256; l0 < (ch + 1) * 256; l0 += 32) {
        for (int i = threadIdx.x; i < 32 * 64; i += 256) {
            const int ll = i >> 6, dd = i & 63;
            ks[ll][dd] = kp[(size_t)(l0 + ll) * HD_ + dd];
            vs[ll][dd] = vp[(size_t)(l0 + ll) * HD_ + dd];
        }
        __syncthreads();
        #pragma unroll
        for (int ll = w * 8; ll < w * 8 + 8; ++ll) {
            float b = (ks[ll][lane] + EPS_) * qsiv;
            #pragma unroll
            for (int off = 32; off >= 1; off >>= 1) b += __shfl_xor(b, off, 64);
            b = fminf(1.f, fmaxf(-1.f, b));
            const float p = expf(b);
            if (lane == 0) pl[ll] = p;
            psum += p;
        }
        __syncthreads();
        #pragma unroll 4
        for (int ll = 0; ll < 32; ++ll) {
            const float vv = vs[ll][lane] * pl[ll];
            #pragma unroll
            for (int dd = 0; dd < 16; ++dd) acc[dd] += ks[ll][w * 16 + dd] * vv;
        }
        __syncthreads();
    }
    #pragma unroll
    for (int dd = 0; dd < 16; ++dd)
        kvp[((size_t)(nh * 8 + ch) * 64 + (w * 16 + dd)) * 64 + lane] = acc[dd];

    __shared__ float sp[4];
    if (lane == 0) sp[w] = psum;
    __syncthreads();
    if (threadIdx.x == 0) psum_p[nh * 8 + ch] = sp[0] + sp[1] + sp[2] + sp[3];
}

// reduce kv partials and apply deferred softmax scale L/tot
__global__ __launch_bounds__(256) void kv_reduce_kernel(
    const float* __restrict__ kvp, const float* __restrict__ psum_p,
    float* __restrict__ kvb)
{
    const int nh = blockIdx.x;
    float tot = 0.f;
    #pragma unroll
    for (int c = 0; c < 8; ++c) tot += psum_p[nh * 8 + c];
    const float scale = (float)L_ / tot;
    for (int e = threadIdx.x; e < 4096; e += 256) {
        float s = 0.f;
        #pragma unroll
        for (int c = 0; c < 8; ++c) s += kvp[(size_t)(nh * 8 + c) * 4096 + e];
        kvb[(size_t)nh * 4096 + e] = s * scale;
    }
}

// ---------------------------------------------------------------------------
// out with fused sink_allocation -> bf16 hi/lo attn store
// ---------------------------------------------------------------------------
__global__ __launch_bounds__(256) void out_kernel(
    const float* __restrict__ q, const float* __restrict__ kvb,
    const float* __restrict__ si, const float* __restrict__ kso,
    short* __restrict__ attn_h, short* __restrict__ attn_l)
{
    const int nh = blockIdx.x;
    const int n = nh >> 4;
    const int h = nh & 15;
    const int l0 = blockIdx.y * 64;
    __shared__ float kvs[64][64];
    __shared__ float qs[64][64];
    __shared__ float sal[64];
    for (int i = threadIdx.x; i < 4096; i += 256)
        kvs[i >> 6][i & 63] = kvb[(size_t)nh * 4096 + i];
    for (int i = threadIdx.x; i < 4096; i += 256) {
        const int ll = i >> 6, dd = i & 63;
        qs[ll][dd] = q[((size_t)nh * L_ + (l0 + ll)) * HD_ + dd];
    }
    __syncthreads();
    const int lane = threadIdx.x & 63;
    const int w = threadIdx.x >> 6;
    const float ksov = kso[nh * 64 + lane] + EPS_;
    for (int ll = w; ll < 64; ll += 4) {
        float a = (qs[ll][lane] + EPS_) * ksov;
        #pragma unroll
        for (int off = 32; off >= 1; off >>= 1) a += __shfl_xor(a, off, 64);
        if (lane == 0) sal[ll] = sigmoidf_(a);
    }
    __syncthreads();
    for (int ll = w; ll < 64; ll += 4) {
        const int l = l0 + ll;
        float acc = 0.f;
        #pragma unroll
        for (int d = 0; d < 64; ++d) acc += qs[ll][d] * kvs[d][lane];
        const float val = acc * si[nh * L_ + l] * sal[ll];
        const size_t idx = ((size_t)n * L_ + l) * DM + h * 64 + lane;
        const short hb = f2bf(val);
        attn_h[idx] = hb;
        attn_l[idx] = f2bf(val - bf2f(hb));
    }
}

extern "C" void kernel_launch(void* const* d_in, const int* in_sizes, int n_in,
                              void* d_out, int out_size, void* d_ws, size_t ws_size,
                              hipStream_t stream)
{
    const float* x  = (const float*)d_in[0];
    const float* Wq = (const float*)d_in[1];
    const float* bq = (const float*)d_in[2];
    const float* Wk = (const float*)d_in[3];
    const float* bk = (const float*)d_in[4];
    const float* Wv = (const float*)d_in[5];
    const float* bv = (const float*)d_in[6];
    const float* Wo = (const float*)d_in[7];
    const float* bo = (const float*)d_in[8];
    float* out = (float*)d_out;

    float* ws = (float*)d_ws;
    size_t off = 0;
    const size_t big = (size_t)B_ * L_ * DM;   // 8,388,608 elems
    float* qbuf = ws + off; off += big;
    float* kbuf = ws + off; off += big;
    float* vbuf = ws + off; off += big;
    short* xh = (short*)(ws + off);
    short* xl = xh + big;
    short* attn_h = xh;
    short* attn_l = xl;
    off += big;
    short* wh3 = (short*)(ws + off); off += (size_t)3 * DM * DM / 2;
    short* wl3 = (short*)(ws + off); off += (size_t)3 * DM * DM / 2;
    short* woh = (short*)(ws + off); off += (size_t)DM * DM / 2;
    short* wol = (short*)(ws + off); off += (size_t)DM * DM / 2;
    float* kvp    = ws + off; off += (size_t)NH_ * 8 * 64 * 64;
    float* kvb    = ws + off; off += (size_t)NH_ * 64 * 64;
    float* sums = ws + off;
    float* qsum = sums;
    float* ksum = sums + 1 * NH_ * 64;
    float* qsi  = sums + 2 * NH_ * 64;
    float* kso  = sums + 3 * NH_ * 64;
    off += 4 * NH_ * 64;
    float* psum_p = ws + off; off += NH_ * 8;
    float* si     = ws + off; off += NH_ * L_;

    // 0. zero the atomic accumulators
    zero_kernel<<<(4 * NH_ * 64 + 255) / 256, 256, 0, stream>>>(sums, 4 * NH_ * 64);

    // 1. split inputs to bf16 hi/lo
    split_kernel<<<big / 4 / 256, 256, 0, stream>>>(x, xh, xl, (int)(big / 4));
    split_w4_kernel<<<dim3(DM * DM / 4 / 256, 4), 256, 0, stream>>>(
        Wq, Wk, Wv, Wo, wh3, wl3, woh, wol);

    // 2. QKV projection: 8-phase 256x256 deep-pipelined GEMM + fused colsum
    gemm_qkv8_kernel<<<384, 512, 0, stream>>>(xh, xl, wh3, wl3, bq, bk, bv,
                                              qbuf, kbuf, vbuf, qsum, ksum);

    // 3. stage1 (si + qsi/kso atomics)
    stage1_part_kernel<<<dim3(NH_, 16), 256, 0, stream>>>(qbuf, kbuf, qsum, ksum, si, qsi, kso);

    // 4. kv with fused source-competition; deferred softmax scale in reduce
    kv_part_kernel<<<dim3(NH_, 8), 256, 0, stream>>>(kbuf, vbuf, qsi, kvp, psum_p);
    kv_reduce_kernel<<<NH_, 256, 0, stream>>>(kvp, psum_p, kvb);

    // 5. out with fused sink_allocation -> bf16 hi/lo attn
    out_kernel<<<dim3(NH_, L_ / 64), 256, 0, stream>>>(qbuf, kvb, si, kso, attn_h, attn_l);

    // 6. output projection GEMM (m97 structure)
    dim3 gout(DM / 128, (B_ * L_) / 128);
    gemm_out_kernel<<<gout, 256, 0, stream>>>(attn_h, attn_l, woh, wol, bo, out);
}

// Round 9
// 353.478 us; speedup vs baseline: 1.2269x; 1.2269x over previous
//
#include <hip/hip_runtime.h>
#include <math.h>

#define B_ 4
#define L_ 2048
#define DM 1024
#define H_ 16
#define HD_ 64
#define NH_ 64            // B_*H_
#define EPS_ 1e-6f

typedef float f32x4 __attribute__((ext_vector_type(4)));
typedef _Float16 half8 __attribute__((ext_vector_type(8)));
typedef _Float16 half4 __attribute__((ext_vector_type(4)));

typedef __attribute__((address_space(3))) void lds_v;
typedef const __attribute__((address_space(1))) void glb_v;
#define GLOAD16(g, l) __builtin_amdgcn_global_load_lds((glb_v*)(g), (lds_v*)(l), 16, 0, 0)

__device__ __forceinline__ float sigmoidf_(float x) { return 1.0f / (1.0f + expf(-x)); }

__global__ __launch_bounds__(256) void zero_kernel(float* __restrict__ p, int n)
{
    const int i = blockIdx.x * 256 + threadIdx.x;
    if (i < n) p[i] = 0.f;
}

// ---------------------------------------------------------------------------
// x -> single f16 (RNE).  Error 2^-11 relative, compensated by W hi/lo split.
// ---------------------------------------------------------------------------
__global__ __launch_bounds__(256) void splitx_kernel(
    const float* __restrict__ in, _Float16* __restrict__ outp, int n4)
{
    const int i = blockIdx.x * 256 + threadIdx.x;
    if (i >= n4) return;
    f32x4 v = *(const f32x4*)(in + (size_t)i * 4);
    half4 h = { (_Float16)v[0], (_Float16)v[1], (_Float16)v[2], (_Float16)v[3] };
    *(half4*)(outp + (size_t)i * 4) = h;
}

// all 4 weights: f16 hi/lo split (W = Wh + Wl to ~2^-22 relative)
__global__ __launch_bounds__(256) void split_w4_kernel(
    const float* __restrict__ Wq, const float* __restrict__ Wk,
    const float* __restrict__ Wv, const float* __restrict__ Wo,
    _Float16* __restrict__ wh3, _Float16* __restrict__ wl3,
    _Float16* __restrict__ woh, _Float16* __restrict__ wol)
{
    const int y = blockIdx.y;
    const float* src = (y == 0) ? Wq : (y == 1) ? Wk : (y == 2) ? Wv : Wo;
    _Float16* hh = (y < 3) ? (wh3 + (size_t)y * DM * DM) : woh;
    _Float16* ll = (y < 3) ? (wl3 + (size_t)y * DM * DM) : wol;
    const int i = blockIdx.x * 256 + threadIdx.x;   // i < DM*DM/4
    f32x4 v = *(const f32x4*)(src + (size_t)i * 4);
    _Float16 h[4], l[4];
    #pragma unroll
    for (int j = 0; j < 4; ++j) {
        h[j] = (_Float16)v[j];
        l[j] = (_Float16)(v[j] - (float)h[j]);
    }
    *(half4*)(hh + (size_t)i * 4) = half4{h[0], h[1], h[2], h[3]};
    *(half4*)(ll + (size_t)i * 4) = half4{l[0], l[1], l[2], l[3]};
}

// ---------------------------------------------------------------------------
// MFMA GEMM core (m97 structure, proven): C[128x128] tile of
// A[M,1024](f16) @ (Wh+Wl)[N,1024]^T — 2-product split-f16.
// LDS 3 planes x [128][32] f16 (24 KB); 16B-slot swizzle (2-way, free);
// linear gload_lds dest + inverse-swizzled source + swizzled ds_read.
// ---------------------------------------------------------------------------
__device__ __forceinline__ void gemm_core(
    const _Float16* __restrict__ A_g,
    const _Float16* __restrict__ Bh_g, const _Float16* __restrict__ Bl_g,
    int row0, int col0, _Float16* lds, f32x4 acc[4][4])
{
    const int t = threadIdx.x;
    const int lane = t & 63;
    const int w = t >> 6;
    const int wr = w >> 1, wc = w & 1;
    const int fr = lane & 15, kc = lane >> 4;

    for (int k0 = 0; k0 < DM; k0 += 32) {
        const _Float16* a_g = A_g  + (size_t)row0 * DM + k0;
        const _Float16* b_h = Bh_g + (size_t)col0 * DM + k0;
        const _Float16* b_l = Bl_g + (size_t)col0 * DM + k0;
        #pragma unroll
        for (int p = 0; p < 2; ++p) {
            const int b = p * 4096 + t * 16;          // linear byte in 8 KB plane
            const int r = b >> 6;                     // row 0..127
            const int s = (b >> 4) & 3;               // 16B slot in row
            const int fsw = (r & 3) ^ ((r >> 2) & 3);
            const int c = ((s ^ fsw) << 3);           // inverse-swizzled k-elem
            const size_t go = (size_t)r * DM + c;
            GLOAD16(a_g + go, lds + 0 * 4096 + (b >> 1));
            GLOAD16(b_h + go, lds + 1 * 4096 + (b >> 1));
            GLOAD16(b_l + go, lds + 2 * 4096 + (b >> 1));
        }
        __syncthreads();

        half8 bhf[4], blf[4];
        #pragma unroll
        for (int n = 0; n < 4; ++n) {
            const int row = wc * 64 + n * 16 + fr;
            const int fsw = (row & 3) ^ ((row >> 2) & 3);
            const int off = row * 32 + ((kc ^ fsw) << 3);
            bhf[n] = *(const half8*)(lds + 1 * 4096 + off);
            blf[n] = *(const half8*)(lds + 2 * 4096 + off);
        }
        #pragma unroll
        for (int m = 0; m < 4; ++m) {
            const int row = wr * 64 + m * 16 + fr;
            const int fsw = (row & 3) ^ ((row >> 2) & 3);
            const int off = row * 32 + ((kc ^ fsw) << 3);
            half8 af = *(const half8*)(lds + 0 * 4096 + off);
            #pragma unroll
            for (int n = 0; n < 4; ++n) {
                acc[m][n] = __builtin_amdgcn_mfma_f32_16x16x32_f16(af, bhf[n], acc[m][n], 0, 0, 0);
                acc[m][n] = __builtin_amdgcn_mfma_f32_16x16x32_f16(af, blf[n], acc[m][n], 0, 0, 0);
            }
        }
        __syncthreads();
    }
}

// QKV GEMM: z selects q/k/v.  Epilogue: +bias, sigmoid for q,k, scatter to
// [B,H,L,HD] f32, fused post-sigmoid colsum -> atomicAdd qsum/ksum.
__global__ __launch_bounds__(256) void gemm_qkv_kernel(
    const _Float16* __restrict__ xf,
    const _Float16* __restrict__ wh, const _Float16* __restrict__ wl,  // [3][DM][DM]
    const float* __restrict__ bq, const float* __restrict__ bk, const float* __restrict__ bv,
    float* __restrict__ qb, float* __restrict__ kb, float* __restrict__ vb,
    float* __restrict__ qsum, float* __restrict__ ksum)
{
    const int z = blockIdx.z;
    const float* __restrict__ bias = (z == 0) ? bq : (z == 1) ? bk : bv;
    float* __restrict__ outp       = (z == 0) ? qb : (z == 1) ? kb : vb;
    const _Float16* Wh = wh + (size_t)z * DM * DM;
    const _Float16* Wl = wl + (size_t)z * DM * DM;

    __shared__ _Float16 lds[3 * 4096];
    const int row0 = blockIdx.y * 128;
    const int col0 = blockIdx.x * 128;
    f32x4 acc[4][4];
    #pragma unroll
    for (int m = 0; m < 4; ++m)
        #pragma unroll
        for (int n = 0; n < 4; ++n) acc[m][n] = f32x4{0.f, 0.f, 0.f, 0.f};

    gemm_core(xf, Wh, Wl, row0, col0, lds, acc);

    const int tid = threadIdx.x;
    const int lane = tid & 63;
    const int w = tid >> 6;
    const int wr = w >> 1, wc = w & 1;
    const int fr = lane & 15, kc = lane >> 4;
    float csum[4] = {0.f, 0.f, 0.f, 0.f};
    #pragma unroll
    for (int m = 0; m < 4; ++m) {
        const int gr0 = row0 + wr * 64 + m * 16 + kc * 4;
        #pragma unroll
        for (int n = 0; n < 4; ++n) {
            const int j = col0 + wc * 64 + n * 16 + fr;
            const float bj = bias[j];
            const int h = j >> 6, dd = j & 63;
            #pragma unroll
            for (int r2 = 0; r2 < 4; ++r2) {
                const int i = gr0 + r2;
                const int nn = i >> 11, l = i & (L_ - 1);
                float v = acc[m][n][r2] + bj;
                if (z < 2) { v = sigmoidf_(v); csum[n] += v; }
                outp[(((size_t)(nn * H_ + h)) * L_ + l) * HD_ + dd] = v;
            }
        }
    }

    if (z < 2) {
        float* scol = (float*)lds;             // LDS free after core's final barrier
        if (tid < 128) scol[tid] = 0.f;
        __syncthreads();
        #pragma unroll
        for (int n = 0; n < 4; ++n)
            atomicAdd(&scol[wc * 64 + n * 16 + fr], csum[n]);
        __syncthreads();
        if (tid < 128) {
            const int j = col0 + tid;
            const int nn = row0 >> 11;
            float* dst = (z == 0) ? qsum : ksum;
            atomicAdd(&dst[(nn * H_ + (j >> 6)) * 64 + (j & 63)], scol[tid]);
        }
    }
}

// Final GEMM: out = attn(f16) @ (Woh+Wol)^T + bo, [B*L, DM] f32 store.
__global__ __launch_bounds__(256) void gemm_out_kernel(
    const _Float16* __restrict__ af,
    const _Float16* __restrict__ wh, const _Float16* __restrict__ wl,
    const float* __restrict__ bias, float* __restrict__ outp)
{
    __shared__ _Float16 lds[3 * 4096];
    const int row0 = blockIdx.y * 128;
    const int col0 = blockIdx.x * 128;
    f32x4 acc[4][4];
    #pragma unroll
    for (int m = 0; m < 4; ++m)
        #pragma unroll
        for (int n = 0; n < 4; ++n) acc[m][n] = f32x4{0.f, 0.f, 0.f, 0.f};

    gemm_core(af, wh, wl, row0, col0, lds, acc);

    const int lane = threadIdx.x & 63;
    const int w = threadIdx.x >> 6;
    const int wr = w >> 1, wc = w & 1;
    const int fr = lane & 15, kc = lane >> 4;
    #pragma unroll
    for (int m = 0; m < 4; ++m) {
        const int gr0 = row0 + wr * 64 + m * 16 + kc * 4;
        #pragma unroll
        for (int n = 0; n < 4; ++n) {
            const int j = col0 + wc * 64 + n * 16 + fr;
            const float bj = bias[j];
            #pragma unroll
            for (int r2 = 0; r2 < 4; ++r2)
                outp[(size_t)(gr0 + r2) * DM + j] = acc[m][n][r2] + bj;
        }
    }
}

// ---------------------------------------------------------------------------
// stage1: per l compute si (stored) and so (inline); atomicAdd qsi/kso.
// ---------------------------------------------------------------------------
__global__ __launch_bounds__(256) void stage1_part_kernel(
    const float* __restrict__ q, const float* __restrict__ k,
    const float* __restrict__ qsum, const float* __restrict__ ksum,
    float* __restrict__ si, float* __restrict__ qsi, float* __restrict__ kso)
{
    const int nh = blockIdx.x, ch = blockIdx.y;
    const float* qp = q + (size_t)nh * L_ * HD_;
    const float* kp = k + (size_t)nh * L_ * HD_;
    const int lane = threadIdx.x & 63;
    const int w = threadIdx.x >> 6;
    const float ksv = ksum[nh * 64 + lane] + EPS_;
    const float qsv = qsum[nh * 64 + lane] + EPS_;
    float qsi_acc = 0.f, kso_acc = 0.f;
    for (int l = ch * 128 + w; l < (ch + 1) * 128; l += 4) {
        const float qv = qp[(size_t)l * HD_ + lane];
        const float kv = kp[(size_t)l * HD_ + lane];
        float a = (qv + EPS_) * ksv;
        float b = (kv + EPS_) * qsv;
        #pragma unroll
        for (int off = 32; off >= 1; off >>= 1) {
            a += __shfl_xor(a, off, 64);
            b += __shfl_xor(b, off, 64);
        }
        const float siv = 1.f / a;
        const float sov = 1.f / b;
        if (lane == 0) si[nh * L_ + l] = siv;
        qsi_acc += qv * siv;
        kso_acc += kv * sov;
    }
    __shared__ float s1[4][64], s2[4][64];
    s1[w][lane] = qsi_acc; s2[w][lane] = kso_acc;
    __syncthreads();
    if (w == 0) {
        atomicAdd(&qsi[nh * 64 + lane], s1[0][lane] + s1[1][lane] + s1[2][lane] + s1[3][lane]);
        atomicAdd(&kso[nh * 64 + lane], s2[0][lane] + s2[1][lane] + s2[2][lane] + s2[3][lane]);
    }
}

// ---------------------------------------------------------------------------
// kv partial over 256-l chunk WITH fused source-competition numerator.
// ---------------------------------------------------------------------------
__global__ __launch_bounds__(256) void kv_part_kernel(
    const float* __restrict__ k, const float* __restrict__ v,
    const float* __restrict__ qsi, float* __restrict__ kvp, float* __restrict__ psum_p)
{
    const int nh = blockIdx.x, ch = blockIdx.y;
    const float* kp = k + (size_t)nh * L_ * HD_;
    const float* vp = v + (size_t)nh * L_ * HD_;
    const int lane = threadIdx.x & 63;
    const int w = threadIdx.x >> 6;
    const float qsiv = qsi[nh * 64 + lane] + EPS_;

    float acc[16] = {0.f};
    float psum = 0.f;
    __shared__ float ks[32][64], vs[32][64];
    __shared__ float pl[32];
    for (int l0 = ch * 256; l0 < (ch + 1) * 256; l0 += 32) {
        for (int i = threadIdx.x; i < 32 * 64; i += 256) {
            const int ll = i >> 6, dd = i & 63;
            ks[ll][dd] = kp[(size_t)(l0 + ll) * HD_ + dd];
            vs[ll][dd] = vp[(size_t)(l0 + ll) * HD_ + dd];
        }
        __syncthreads();
        #pragma unroll
        for (int ll = w * 8; ll < w * 8 + 8; ++ll) {
            float b = (ks[ll][lane] + EPS_) * qsiv;
            #pragma unroll
            for (int off = 32; off >= 1; off >>= 1) b += __shfl_xor(b, off, 64);
            b = fminf(1.f, fmaxf(-1.f, b));
            const float p = expf(b);
            if (lane == 0) pl[ll] = p;
            psum += p;
        }
        __syncthreads();
        #pragma unroll 4
        for (int ll = 0; ll < 32; ++ll) {
            const float vv = vs[ll][lane] * pl[ll];
            #pragma unroll
            for (int dd = 0; dd < 16; ++dd) acc[dd] += ks[ll][w * 16 + dd] * vv;
        }
        __syncthreads();
    }
    #pragma unroll
    for (int dd = 0; dd < 16; ++dd)
        kvp[((size_t)(nh * 8 + ch) * 64 + (w * 16 + dd)) * 64 + lane] = acc[dd];

    __shared__ float sp[4];
    if (lane == 0) sp[w] = psum;
    __syncthreads();
    if (threadIdx.x == 0) psum_p[nh * 8 + ch] = sp[0] + sp[1] + sp[2] + sp[3];
}

// reduce kv partials and apply deferred softmax scale L/tot
__global__ __launch_bounds__(256) void kv_reduce_kernel(
    const float* __restrict__ kvp, const float* __restrict__ psum_p,
    float* __restrict__ kvb)
{
    const int nh = blockIdx.x;
    float tot = 0.f;
    #pragma unroll
    for (int c = 0; c < 8; ++c) tot += psum_p[nh * 8 + c];
    const float scale = (float)L_ / tot;
    for (int e = threadIdx.x; e < 4096; e += 256) {
        float s = 0.f;
        #pragma unroll
        for (int c = 0; c < 8; ++c) s += kvp[(size_t)(nh * 8 + c) * 4096 + e];
        kvb[(size_t)nh * 4096 + e] = s * scale;
    }
}

// ---------------------------------------------------------------------------
// out with fused sink_allocation -> single-f16 attn store
// ---------------------------------------------------------------------------
__global__ __launch_bounds__(256) void out_kernel(
    const float* __restrict__ q, const float* __restrict__ kvb,
    const float* __restrict__ si, const float* __restrict__ kso,
    _Float16* __restrict__ attn_f)
{
    const int nh = blockIdx.x;
    const int n = nh >> 4;
    const int h = nh & 15;
    const int l0 = blockIdx.y * 64;
    __shared__ float kvs[64][64];
    __shared__ float qs[64][64];
    __shared__ float sal[64];
    for (int i = threadIdx.x; i < 4096; i += 256)
        kvs[i >> 6][i & 63] = kvb[(size_t)nh * 4096 + i];
    for (int i = threadIdx.x; i < 4096; i += 256) {
        const int ll = i >> 6, dd = i & 63;
        qs[ll][dd] = q[((size_t)nh * L_ + (l0 + ll)) * HD_ + dd];
    }
    __syncthreads();
    const int lane = threadIdx.x & 63;
    const int w = threadIdx.x >> 6;
    const float ksov = kso[nh * 64 + lane] + EPS_;
    for (int ll = w; ll < 64; ll += 4) {
        float a = (qs[ll][lane] + EPS_) * ksov;
        #pragma unroll
        for (int off = 32; off >= 1; off >>= 1) a += __shfl_xor(a, off, 64);
        if (lane == 0) sal[ll] = sigmoidf_(a);
    }
    __syncthreads();
    for (int ll = w; ll < 64; ll += 4) {
        const int l = l0 + ll;
        float acc = 0.f;
        #pragma unroll
        for (int d = 0; d < 64; ++d) acc += qs[ll][d] * kvs[d][lane];
        const float val = acc * si[nh * L_ + l] * sal[ll];
        attn_f[((size_t)n * L_ + l) * DM + h * 64 + lane] = (_Float16)val;
    }
}

extern "C" void kernel_launch(void* const* d_in, const int* in_sizes, int n_in,
                              void* d_out, int out_size, void* d_ws, size_t ws_size,
                              hipStream_t stream)
{
    const float* x  = (const float*)d_in[0];
    const float* Wq = (const float*)d_in[1];
    const float* bq = (const float*)d_in[2];
    const float* Wk = (const float*)d_in[3];
    const float* bk = (const float*)d_in[4];
    const float* Wv = (const float*)d_in[5];
    const float* bv = (const float*)d_in[6];
    const float* Wo = (const float*)d_in[7];
    const float* bo = (const float*)d_in[8];
    float* out = (float*)d_out;

    float* ws = (float*)d_ws;
    size_t off = 0;
    const size_t big = (size_t)B_ * L_ * DM;   // 8,388,608 elems
    float* qbuf = ws + off; off += big;
    float* kbuf = ws + off; off += big;
    float* vbuf = ws + off; off += big;
    // union region: x f16 during projections, attn f16 afterwards (big halves)
    _Float16* xf = (_Float16*)(ws + off);
    _Float16* attn_f = xf;
    off += big / 2;
    _Float16* wh3 = (_Float16*)(ws + off); off += (size_t)3 * DM * DM / 2;
    _Float16* wl3 = (_Float16*)(ws + off); off += (size_t)3 * DM * DM / 2;
    _Float16* woh = (_Float16*)(ws + off); off += (size_t)DM * DM / 2;
    _Float16* wol = (_Float16*)(ws + off); off += (size_t)DM * DM / 2;
    float* kvp    = ws + off; off += (size_t)NH_ * 8 * 64 * 64;
    float* kvb    = ws + off; off += (size_t)NH_ * 64 * 64;
    float* sums = ws + off;
    float* qsum = sums;
    float* ksum = sums + 1 * NH_ * 64;
    float* qsi  = sums + 2 * NH_ * 64;
    float* kso  = sums + 3 * NH_ * 64;
    off += 4 * NH_ * 64;
    float* psum_p = ws + off; off += NH_ * 8;
    float* si     = ws + off; off += NH_ * L_;

    // 0. zero the atomic accumulators
    zero_kernel<<<(4 * NH_ * 64 + 255) / 256, 256, 0, stream>>>(sums, 4 * NH_ * 64);

    // 1. x -> f16; weights -> f16 hi/lo
    splitx_kernel<<<big / 4 / 256, 256, 0, stream>>>(x, xf, (int)(big / 4));
    split_w4_kernel<<<dim3(DM * DM / 4 / 256, 4), 256, 0, stream>>>(
        Wq, Wk, Wv, Wo, wh3, wl3, woh, wol);

    // 2. QKV projection GEMMs (2-product split-f16 MFMA) + fused colsum
    dim3 gqkv(DM / 128, (B_ * L_) / 128, 3);
    gemm_qkv_kernel<<<gqkv, 256, 0, stream>>>(xf, wh3, wl3, bq, bk, bv,
                                              qbuf, kbuf, vbuf, qsum, ksum);

    // 3. stage1 (si + qsi/kso atomics)
    stage1_part_kernel<<<dim3(NH_, 16), 256, 0, stream>>>(qbuf, kbuf, qsum, ksum, si, qsi, kso);

    // 4. kv with fused source-competition; deferred softmax scale in reduce
    kv_part_kernel<<<dim3(NH_, 8), 256, 0, stream>>>(kbuf, vbuf, qsi, kvp, psum_p);
    kv_reduce_kernel<<<NH_, 256, 0, stream>>>(kvp, psum_p, kvb);

    // 5. out with fused sink_allocation -> f16 attn
    out_kernel<<<dim3(NH_, L_ / 64), 256, 0, stream>>>(qbuf, kvb, si, kso, attn_f);

    // 6. output projection GEMM (2-product split-f16)
    dim3 gout(DM / 128, (B_ * L_) / 128);
    gemm_out_kernel<<<gout, 256, 0, stream>>>(attn_f, woh, wol, bo, out);
}

// Round 10
// 311.883 us; speedup vs baseline: 1.3906x; 1.1334x over previous
//
#include <hip/hip_runtime.h>
#include <math.h>

#define B_ 4
#define L_ 2048
#define DM 1024
#define H_ 16
#define HD_ 64
#define NH_ 64            // B_*H_
#define EPS_ 1e-6f

typedef float f32x4 __attribute__((ext_vector_type(4)));
typedef _Float16 half8 __attribute__((ext_vector_type(8)));
typedef _Float16 half4 __attribute__((ext_vector_type(4)));

typedef __attribute__((address_space(3))) void lds_v;
typedef const __attribute__((address_space(1))) void glb_v;
#define GLOAD16(g, l) __builtin_amdgcn_global_load_lds((glb_v*)(g), (lds_v*)(l), 16, 0, 0)

__device__ __forceinline__ float sigmoidf_(float x) { return 1.0f / (1.0f + expf(-x)); }

__global__ __launch_bounds__(256) void zero_kernel(float* __restrict__ p, int n)
{
    const int i = blockIdx.x * 256 + threadIdx.x;
    if (i < n) p[i] = 0.f;
}

// ---------------------------------------------------------------------------
// x -> single f16 (RNE).
// ---------------------------------------------------------------------------
__global__ __launch_bounds__(256) void splitx_kernel(
    const float* __restrict__ in, _Float16* __restrict__ outp, int n4)
{
    const int i = blockIdx.x * 256 + threadIdx.x;
    if (i >= n4) return;
    f32x4 v = *(const f32x4*)(in + (size_t)i * 4);
    half4 h = { (_Float16)v[0], (_Float16)v[1], (_Float16)v[2], (_Float16)v[3] };
    *(half4*)(outp + (size_t)i * 4) = h;
}

// weights: Wq/Wk/Wv -> f16 hi only; Wo -> f16 hi/lo (out GEMM keeps 2-product)
__global__ __launch_bounds__(256) void split_w4_kernel(
    const float* __restrict__ Wq, const float* __restrict__ Wk,
    const float* __restrict__ Wv, const float* __restrict__ Wo,
    _Float16* __restrict__ wh3, _Float16* __restrict__ woh, _Float16* __restrict__ wol)
{
    const int y = blockIdx.y;
    const float* src = (y == 0) ? Wq : (y == 1) ? Wk : (y == 2) ? Wv : Wo;
    _Float16* hh = (y < 3) ? (wh3 + (size_t)y * DM * DM) : woh;
    const int i = blockIdx.x * 256 + threadIdx.x;   // i < DM*DM/4
    f32x4 v = *(const f32x4*)(src + (size_t)i * 4);
    _Float16 h[4], l[4];
    #pragma unroll
    for (int j = 0; j < 4; ++j) {
        h[j] = (_Float16)v[j];
        l[j] = (_Float16)(v[j] - (float)h[j]);
    }
    *(half4*)(hh + (size_t)i * 4) = half4{h[0], h[1], h[2], h[3]};
    if (y == 3)
        *(half4*)(wol + (size_t)i * 4) = half4{l[0], l[1], l[2], l[3]};
}

// ===========================================================================
// QKV GEMM: single-product f16, BK=64, m97 structure.
//   C[128x128] tile of x_f16[M,1024] @ Wh[N,1024]^T.  LDS 2 planes x
//   [128 rows][64 k] f16 (16 KB each).  8-slot swizzle: slot' = slot^(row&7)
//   on 16B slots of 128B rows (2 lanes/slot-group per quarter = free min).
//   Linear gload_lds dest + inverse-swizzled source k-offset + swizzled read.
//   Epilogue: +bias, sigmoid q/k, scatter [B,H,L,HD] f32, fused colsum.
// ===========================================================================
__global__ __launch_bounds__(256) void gemm_qkv_kernel(
    const _Float16* __restrict__ xf,
    const _Float16* __restrict__ wh,                               // [3][DM][DM]
    const float* __restrict__ bq, const float* __restrict__ bk, const float* __restrict__ bv,
    float* __restrict__ qb, float* __restrict__ kb, float* __restrict__ vb,
    float* __restrict__ qsum, float* __restrict__ ksum)
{
    const int z = blockIdx.z;
    const float* __restrict__ bias = (z == 0) ? bq : (z == 1) ? bk : bv;
    float* __restrict__ outp       = (z == 0) ? qb : (z == 1) ? kb : vb;
    const _Float16* Wh = wh + (size_t)z * DM * DM;

    __shared__ _Float16 lds[2 * 8192];   // A plane | B plane, 16 KB each
    const int row0 = blockIdx.y * 128;
    const int col0 = blockIdx.x * 128;
    const int t = threadIdx.x;
    const int lane = t & 63;
    const int w = t >> 6;
    const int wr = w >> 1, wc = w & 1;
    const int fr = lane & 15, kc = lane >> 4;

    f32x4 acc[4][4];
    #pragma unroll
    for (int m = 0; m < 4; ++m)
        #pragma unroll
        for (int n = 0; n < 4; ++n) acc[m][n] = f32x4{0.f, 0.f, 0.f, 0.f};

    for (int k0 = 0; k0 < DM; k0 += 64) {
        const _Float16* a_g = xf + (size_t)row0 * DM + k0;
        const _Float16* b_g = Wh + (size_t)col0 * DM + k0;
        #pragma unroll
        for (int p = 0; p < 4; ++p) {
            const int b = p * 4096 + t * 16;          // byte in 16 KB plane
            const int r = b >> 7;                     // row 0..127
            const int s = (b >> 4) & 7;               // 16B slot in 128B row
            const int c = ((s ^ (r & 7)) << 3);       // inverse-swizzled k-elem
            const size_t go = (size_t)r * DM + c;
            GLOAD16(a_g + go, lds + (b >> 1));
            GLOAD16(b_g + go, lds + 8192 + (b >> 1));
        }
        __syncthreads();

        #pragma unroll
        for (int ks = 0; ks < 2; ++ks) {
            const int sl = (ks << 2) | kc;
            half8 bf[4];
            #pragma unroll
            for (int n = 0; n < 4; ++n) {
                const int row = wc * 64 + n * 16 + fr;
                bf[n] = *(const half8*)(lds + 8192 + row * 64 + ((sl ^ (row & 7)) << 3));
            }
            #pragma unroll
            for (int m = 0; m < 4; ++m) {
                const int row = wr * 64 + m * 16 + fr;
                half8 af = *(const half8*)(lds + row * 64 + ((sl ^ (row & 7)) << 3));
                #pragma unroll
                for (int n = 0; n < 4; ++n)
                    acc[m][n] = __builtin_amdgcn_mfma_f32_16x16x32_f16(af, bf[n], acc[m][n], 0, 0, 0);
            }
        }
        __syncthreads();
    }

    float csum[4] = {0.f, 0.f, 0.f, 0.f};
    #pragma unroll
    for (int m = 0; m < 4; ++m) {
        const int gr0 = row0 + wr * 64 + m * 16 + kc * 4;
        #pragma unroll
        for (int n = 0; n < 4; ++n) {
            const int j = col0 + wc * 64 + n * 16 + fr;
            const float bj = bias[j];
            const int h = j >> 6, dd = j & 63;
            #pragma unroll
            for (int r2 = 0; r2 < 4; ++r2) {
                const int i = gr0 + r2;
                const int nn = i >> 11, l = i & (L_ - 1);
                float v = acc[m][n][r2] + bj;
                if (z < 2) { v = sigmoidf_(v); csum[n] += v; }
                outp[(((size_t)(nn * H_ + h)) * L_ + l) * HD_ + dd] = v;
            }
        }
    }

    if (z < 2) {
        float* scol = (float*)lds;             // LDS free after final barrier
        if (t < 128) scol[t] = 0.f;
        __syncthreads();
        #pragma unroll
        for (int n = 0; n < 4; ++n)
            atomicAdd(&scol[wc * 64 + n * 16 + fr], csum[n]);
        __syncthreads();
        if (t < 128) {
            const int j = col0 + t;
            const int nn = row0 >> 11;
            float* dst = (z == 0) ? qsum : ksum;
            atomicAdd(&dst[(nn * H_ + (j >> 6)) * 64 + (j & 63)], scol[t]);
        }
    }
}

// ---------------------------------------------------------------------------
// Output GEMM: 2-product split-f16 (attn @ (Woh+Wol)^T + bo), m97 structure,
// BK=32, 3 LDS planes — unchanged proven R9 kernel.
// ---------------------------------------------------------------------------
__device__ __forceinline__ void gemm_core(
    const _Float16* __restrict__ A_g,
    const _Float16* __restrict__ Bh_g, const _Float16* __restrict__ Bl_g,
    int row0, int col0, _Float16* lds, f32x4 acc[4][4])
{
    const int t = threadIdx.x;
    const int lane = t & 63;
    const int w = t >> 6;
    const int wr = w >> 1, wc = w & 1;
    const int fr = lane & 15, kc = lane >> 4;

    for (int k0 = 0; k0 < DM; k0 += 32) {
        const _Float16* a_g = A_g  + (size_t)row0 * DM + k0;
        const _Float16* b_h = Bh_g + (size_t)col0 * DM + k0;
        const _Float16* b_l = Bl_g + (size_t)col0 * DM + k0;
        #pragma unroll
        for (int p = 0; p < 2; ++p) {
            const int b = p * 4096 + t * 16;
            const int r = b >> 6;
            const int s = (b >> 4) & 3;
            const int fsw = (r & 3) ^ ((r >> 2) & 3);
            const int c = ((s ^ fsw) << 3);
            const size_t go = (size_t)r * DM + c;
            GLOAD16(a_g + go, lds + 0 * 4096 + (b >> 1));
            GLOAD16(b_h + go, lds + 1 * 4096 + (b >> 1));
            GLOAD16(b_l + go, lds + 2 * 4096 + (b >> 1));
        }
        __syncthreads();

        half8 bhf[4], blf[4];
        #pragma unroll
        for (int n = 0; n < 4; ++n) {
            const int row = wc * 64 + n * 16 + fr;
            const int fsw = (row & 3) ^ ((row >> 2) & 3);
            const int off = row * 32 + ((kc ^ fsw) << 3);
            bhf[n] = *(const half8*)(lds + 1 * 4096 + off);
            blf[n] = *(const half8*)(lds + 2 * 4096 + off);
        }
        #pragma unroll
        for (int m = 0; m < 4; ++m) {
            const int row = wr * 64 + m * 16 + fr;
            const int fsw = (row & 3) ^ ((row >> 2) & 3);
            const int off = row * 32 + ((kc ^ fsw) << 3);
            half8 af = *(const half8*)(lds + 0 * 4096 + off);
            #pragma unroll
            for (int n = 0; n < 4; ++n) {
                acc[m][n] = __builtin_amdgcn_mfma_f32_16x16x32_f16(af, bhf[n], acc[m][n], 0, 0, 0);
                acc[m][n] = __builtin_amdgcn_mfma_f32_16x16x32_f16(af, blf[n], acc[m][n], 0, 0, 0);
            }
        }
        __syncthreads();
    }
}

__global__ __launch_bounds__(256) void gemm_out_kernel(
    const _Float16* __restrict__ af,
    const _Float16* __restrict__ wh, const _Float16* __restrict__ wl,
    const float* __restrict__ bias, float* __restrict__ outp)
{
    __shared__ _Float16 lds[3 * 4096];
    const int row0 = blockIdx.y * 128;
    const int col0 = blockIdx.x * 128;
    f32x4 acc[4][4];
    #pragma unroll
    for (int m = 0; m < 4; ++m)
        #pragma unroll
        for (int n = 0; n < 4; ++n) acc[m][n] = f32x4{0.f, 0.f, 0.f, 0.f};

    gemm_core(af, wh, wl, row0, col0, lds, acc);

    const int lane = threadIdx.x & 63;
    const int w = threadIdx.x >> 6;
    const int wr = w >> 1, wc = w & 1;
    const int fr = lane & 15, kc = lane >> 4;
    #pragma unroll
    for (int m = 0; m < 4; ++m) {
        const int gr0 = row0 + wr * 64 + m * 16 + kc * 4;
        #pragma unroll
        for (int n = 0; n < 4; ++n) {
            const int j = col0 + wc * 64 + n * 16 + fr;
            const float bj = bias[j];
            #pragma unroll
            for (int r2 = 0; r2 < 4; ++r2)
                outp[(size_t)(gr0 + r2) * DM + j] = acc[m][n][r2] + bj;
        }
    }
}

// ---------------------------------------------------------------------------
// stage1: per l compute si (stored) and so (inline); atomicAdd qsi/kso.
// ---------------------------------------------------------------------------
__global__ __launch_bounds__(256) void stage1_part_kernel(
    const float* __restrict__ q, const float* __restrict__ k,
    const float* __restrict__ qsum, const float* __restrict__ ksum,
    float* __restrict__ si, float* __restrict__ qsi, float* __restrict__ kso)
{
    const int nh = blockIdx.x, ch = blockIdx.y;
    const float* qp = q + (size_t)nh * L_ * HD_;
    const float* kp = k + (size_t)nh * L_ * HD_;
    const int lane = threadIdx.x & 63;
    const int w = threadIdx.x >> 6;
    const float ksv = ksum[nh * 64 + lane] + EPS_;
    const float qsv = qsum[nh * 64 + lane] + EPS_;
    float qsi_acc = 0.f, kso_acc = 0.f;
    for (int l = ch * 128 + w; l < (ch + 1) * 128; l += 4) {
        const float qv = qp[(size_t)l * HD_ + lane];
        const float kv = kp[(size_t)l * HD_ + lane];
        float a = (qv + EPS_) * ksv;
        float b = (kv + EPS_) * qsv;
        #pragma unroll
        for (int off = 32; off >= 1; off >>= 1) {
            a += __shfl_xor(a, off, 64);
            b += __shfl_xor(b, off, 64);
        }
        const float siv = 1.f / a;
        const float sov = 1.f / b;
        if (lane == 0) si[nh * L_ + l] = siv;
        qsi_acc += qv * siv;
        kso_acc += kv * sov;
    }
    __shared__ float s1[4][64], s2[4][64];
    s1[w][lane] = qsi_acc; s2[w][lane] = kso_acc;
    __syncthreads();
    if (w == 0) {
        atomicAdd(&qsi[nh * 64 + lane], s1[0][lane] + s1[1][lane] + s1[2][lane] + s1[3][lane]);
        atomicAdd(&kso[nh * 64 + lane], s2[0][lane] + s2[1][lane] + s2[2][lane] + s2[3][lane]);
    }
}

// ---------------------------------------------------------------------------
// kv partial over 256-l chunk WITH fused source-competition numerator.
// ---------------------------------------------------------------------------
__global__ __launch_bounds__(256) void kv_part_kernel(
    const float* __restrict__ k, const float* __restrict__ v,
    const float* __restrict__ qsi, float* __restrict__ kvp, float* __restrict__ psum_p)
{
    const int nh = blockIdx.x, ch = blockIdx.y;
    const float* kp = k + (size_t)nh * L_ * HD_;
    const float* vp = v + (size_t)nh * L_ * HD_;
    const int lane = threadIdx.x & 63;
    const int w = threadIdx.x >> 6;
    const float qsiv = qsi[nh * 64 + lane] + EPS_;

    float acc[16] = {0.f};
    float psum = 0.f;
    __shared__ float ks[32][64], vs[32][64];
    __shared__ float pl[32];
    for (int l0 = ch * 256; l0 < (ch + 1) * 256; l0 += 32) {
        for (int i = threadIdx.x; i < 32 * 64; i += 256) {
            const int ll = i >> 6, dd = i & 63;
            ks[ll][dd] = kp[(size_t)(l0 + ll) * HD_ + dd];
            vs[ll][dd] = vp[(size_t)(l0 + ll) * HD_ + dd];
        }
        __syncthreads();
        #pragma unroll
        for (int ll = w * 8; ll < w * 8 + 8; ++ll) {
            float b = (ks[ll][lane] + EPS_) * qsiv;
            #pragma unroll
            for (int off = 32; off >= 1; off >>= 1) b += __shfl_xor(b, off, 64);
            b = fminf(1.f, fmaxf(-1.f, b));
            const float p = expf(b);
            if (lane == 0) pl[ll] = p;
            psum += p;
        }
        __syncthreads();
        #pragma unroll 4
        for (int ll = 0; ll < 32; ++ll) {
            const float vv = vs[ll][lane] * pl[ll];
            #pragma unroll
            for (int dd = 0; dd < 16; ++dd) acc[dd] += ks[ll][w * 16 + dd] * vv;
        }
        __syncthreads();
    }
    #pragma unroll
    for (int dd = 0; dd < 16; ++dd)
        kvp[((size_t)(nh * 8 + ch) * 64 + (w * 16 + dd)) * 64 + lane] = acc[dd];

    __shared__ float sp[4];
    if (lane == 0) sp[w] = psum;
    __syncthreads();
    if (threadIdx.x == 0) psum_p[nh * 8 + ch] = sp[0] + sp[1] + sp[2] + sp[3];
}

// reduce kv partials and apply deferred softmax scale L/tot
__global__ __launch_bounds__(256) void kv_reduce_kernel(
    const float* __restrict__ kvp, const float* __restrict__ psum_p,
    float* __restrict__ kvb)
{
    const int nh = blockIdx.x;
    float tot = 0.f;
    #pragma unroll
    for (int c = 0; c < 8; ++c) tot += psum_p[nh * 8 + c];
    const float scale = (float)L_ / tot;
    for (int e = threadIdx.x; e < 4096; e += 256) {
        float s = 0.f;
        #pragma unroll
        for (int c = 0; c < 8; ++c) s += kvp[(size_t)(nh * 8 + c) * 4096 + e];
        kvb[(size_t)nh * 4096 + e] = s * scale;
    }
}

// ---------------------------------------------------------------------------
// out with fused sink_allocation -> single-f16 attn store
// ---------------------------------------------------------------------------
__global__ __launch_bounds__(256) void out_kernel(
    const float* __restrict__ q, const float* __restrict__ kvb,
    const float* __restrict__ si, const float* __restrict__ kso,
    _Float16* __restrict__ attn_f)
{
    const int nh = blockIdx.x;
    const int n = nh >> 4;
    const int h = nh & 15;
    const int l0 = blockIdx.y * 64;
    __shared__ float kvs[64][64];
    __shared__ float qs[64][64];
    __shared__ float sal[64];
    for (int i = threadIdx.x; i < 4096; i += 256)
        kvs[i >> 6][i & 63] = kvb[(size_t)nh * 4096 + i];
    for (int i = threadIdx.x; i < 4096; i += 256) {
        const int ll = i >> 6, dd = i & 63;
        qs[ll][dd] = q[((size_t)nh * L_ + (l0 + ll)) * HD_ + dd];
    }
    __syncthreads();
    const int lane = threadIdx.x & 63;
    const int w = threadIdx.x >> 6;
    const float ksov = kso[nh * 64 + lane] + EPS_;
    for (int ll = w; ll < 64; ll += 4) {
        float a = (qs[ll][lane] + EPS_) * ksov;
        #pragma unroll
        for (int off = 32; off >= 1; off >>= 1) a += __shfl_xor(a, off, 64);
        if (lane == 0) sal[ll] = sigmoidf_(a);
    }
    __syncthreads();
    for (int ll = w; ll < 64; ll += 4) {
        const int l = l0 + ll;
        float acc = 0.f;
        #pragma unroll
        for (int d = 0; d < 64; ++d) acc += qs[ll][d] * kvs[d][lane];
        const float val = acc * si[nh * L_ + l] * sal[ll];
        attn_f[((size_t)n * L_ + l) * DM + h * 64 + lane] = (_Float16)val;
    }
}

extern "C" void kernel_launch(void* const* d_in, const int* in_sizes, int n_in,
                              void* d_out, int out_size, void* d_ws, size_t ws_size,
                              hipStream_t stream)
{
    const float* x  = (const float*)d_in[0];
    const float* Wq = (const float*)d_in[1];
    const float* bq = (const float*)d_in[2];
    const float* Wk = (const float*)d_in[3];
    const float* bk = (const float*)d_in[4];
    const float* Wv = (const float*)d_in[5];
    const float* bv = (const float*)d_in[6];
    const float* Wo = (const float*)d_in[7];
    const float* bo = (const float*)d_in[8];
    float* out = (float*)d_out;

    float* ws = (float*)d_ws;
    size_t off = 0;
    const size_t big = (size_t)B_ * L_ * DM;   // 8,388,608 elems
    float* qbuf = ws + off; off += big;
    float* kbuf = ws + off; off += big;
    float* vbuf = ws + off; off += big;
    // union region: x f16 during projections, attn f16 afterwards (big halves)
    _Float16* xf = (_Float16*)(ws + off);
    _Float16* attn_f = xf;
    off += big / 2;
    _Float16* wh3 = (_Float16*)(ws + off); off += (size_t)3 * DM * DM / 2;
    _Float16* woh = (_Float16*)(ws + off); off += (size_t)DM * DM / 2;
    _Float16* wol = (_Float16*)(ws + off); off += (size_t)DM * DM / 2;
    float* kvp    = ws + off; off += (size_t)NH_ * 8 * 64 * 64;
    float* kvb    = ws + off; off += (size_t)NH_ * 64 * 64;
    float* sums = ws + off;
    float* qsum = sums;
    float* ksum = sums + 1 * NH_ * 64;
    float* qsi  = sums + 2 * NH_ * 64;
    float* kso  = sums + 3 * NH_ * 64;
    off += 4 * NH_ * 64;
    float* psum_p = ws + off; off += NH_ * 8;
    float* si     = ws + off; off += NH_ * L_;

    // 0. zero the atomic accumulators
    zero_kernel<<<(4 * NH_ * 64 + 255) / 256, 256, 0, stream>>>(sums, 4 * NH_ * 64);

    // 1. x -> f16; Wq/Wk/Wv -> f16 hi; Wo -> f16 hi/lo
    splitx_kernel<<<big / 4 / 256, 256, 0, stream>>>(x, xf, (int)(big / 4));
    split_w4_kernel<<<dim3(DM * DM / 4 / 256, 4), 256, 0, stream>>>(
        Wq, Wk, Wv, Wo, wh3, woh, wol);

    // 2. QKV projection GEMMs (single-product f16, BK=64) + fused colsum
    dim3 gqkv(DM / 128, (B_ * L_) / 128, 3);
    gemm_qkv_kernel<<<gqkv, 256, 0, stream>>>(xf, wh3, bq, bk, bv,
                                              qbuf, kbuf, vbuf, qsum, ksum);

    // 3. stage1 (si + qsi/kso atomics)
    stage1_part_kernel<<<dim3(NH_, 16), 256, 0, stream>>>(qbuf, kbuf, qsum, ksum, si, qsi, kso);

    // 4. kv with fused source-competition; deferred softmax scale in reduce
    kv_part_kernel<<<dim3(NH_, 8), 256, 0, stream>>>(kbuf, vbuf, qsi, kvp, psum_p);
    kv_reduce_kernel<<<NH_, 256, 0, stream>>>(kvp, psum_p, kvb);

    // 5. out with fused sink_allocation -> f16 attn
    out_kernel<<<dim3(NH_, L_ / 64), 256, 0, stream>>>(qbuf, kvb, si, kso, attn_f);

    // 6. output projection GEMM (2-product split-f16)
    dim3 gout(DM / 128, (B_ * L_) / 128);
    gemm_out_kernel<<<gout, 256, 0, stream>>>(attn_f, woh, wol, bo, out);
}

// Round 11
// 298.795 us; speedup vs baseline: 1.4515x; 1.0438x over previous
//
#include <hip/hip_runtime.h>
#include <math.h>

#define B_ 4
#define L_ 2048
#define DM 1024
#define H_ 16
#define HD_ 64
#define NH_ 64            // B_*H_
#define EPS_ 1e-6f

typedef float f32x4 __attribute__((ext_vector_type(4)));
typedef _Float16 half8 __attribute__((ext_vector_type(8)));
typedef _Float16 half4 __attribute__((ext_vector_type(4)));

typedef __attribute__((address_space(3))) void lds_v;
typedef const __attribute__((address_space(1))) void glb_v;
#define GLOAD16(g, l) __builtin_amdgcn_global_load_lds((glb_v*)(g), (lds_v*)(l), 16, 0, 0)

__device__ __forceinline__ float sigmoidf_(float x) { return 1.0f / (1.0f + expf(-x)); }

__global__ __launch_bounds__(256) void zero_kernel(float* __restrict__ p, int n)
{
    const int i = blockIdx.x * 256 + threadIdx.x;
    if (i < n) p[i] = 0.f;
}

// ---------------------------------------------------------------------------
// x -> f16 (RNE)
// ---------------------------------------------------------------------------
__global__ __launch_bounds__(256) void splitx_kernel(
    const float* __restrict__ in, _Float16* __restrict__ outp, int n4)
{
    const int i = blockIdx.x * 256 + threadIdx.x;
    if (i >= n4) return;
    f32x4 v = *(const f32x4*)(in + (size_t)i * 4);
    half4 h = { (_Float16)v[0], (_Float16)v[1], (_Float16)v[2], (_Float16)v[3] };
    *(half4*)(outp + (size_t)i * 4) = h;
}

// all 4 weights -> f16 hi only (single-product GEMMs everywhere)
__global__ __launch_bounds__(256) void split_w4_kernel(
    const float* __restrict__ Wq, const float* __restrict__ Wk,
    const float* __restrict__ Wv, const float* __restrict__ Wo,
    _Float16* __restrict__ wh3, _Float16* __restrict__ woh)
{
    const int y = blockIdx.y;
    const float* src = (y == 0) ? Wq : (y == 1) ? Wk : (y == 2) ? Wv : Wo;
    _Float16* hh = (y < 3) ? (wh3 + (size_t)y * DM * DM) : woh;
    const int i = blockIdx.x * 256 + threadIdx.x;   // i < DM*DM/4
    f32x4 v = *(const f32x4*)(src + (size_t)i * 4);
    half4 h = { (_Float16)v[0], (_Float16)v[1], (_Float16)v[2], (_Float16)v[3] };
    *(half4*)(hh + (size_t)i * 4) = h;
}

// ===========================================================================
// QKV GEMM: single-product f16, BK=64, m97 structure (proven R10).
//   Epilogue: +bias, sigmoid q/k, scatter [B,H,L,HD] **f16**, fused colsum.
// ===========================================================================
__global__ __launch_bounds__(256) void gemm_qkv_kernel(
    const _Float16* __restrict__ xf,
    const _Float16* __restrict__ wh,                               // [3][DM][DM]
    const float* __restrict__ bq, const float* __restrict__ bk, const float* __restrict__ bv,
    _Float16* __restrict__ qb, _Float16* __restrict__ kb, _Float16* __restrict__ vb,
    float* __restrict__ qsum, float* __restrict__ ksum)
{
    const int z = blockIdx.z;
    const float* __restrict__ bias  = (z == 0) ? bq : (z == 1) ? bk : bv;
    _Float16* __restrict__ outp     = (z == 0) ? qb : (z == 1) ? kb : vb;
    const _Float16* Wh = wh + (size_t)z * DM * DM;

    __shared__ _Float16 lds[2 * 8192];   // A plane | B plane, 16 KB each
    const int row0 = blockIdx.y * 128;
    const int col0 = blockIdx.x * 128;
    const int t = threadIdx.x;
    const int lane = t & 63;
    const int w = t >> 6;
    const int wr = w >> 1, wc = w & 1;
    const int fr = lane & 15, kc = lane >> 4;

    f32x4 acc[4][4];
    #pragma unroll
    for (int m = 0; m < 4; ++m)
        #pragma unroll
        for (int n = 0; n < 4; ++n) acc[m][n] = f32x4{0.f, 0.f, 0.f, 0.f};

    for (int k0 = 0; k0 < DM; k0 += 64) {
        const _Float16* a_g = xf + (size_t)row0 * DM + k0;
        const _Float16* b_g = Wh + (size_t)col0 * DM + k0;
        #pragma unroll
        for (int p = 0; p < 4; ++p) {
            const int b = p * 4096 + t * 16;          // byte in 16 KB plane
            const int r = b >> 7;                     // row 0..127
            const int s = (b >> 4) & 7;               // 16B slot in 128B row
            const int c = ((s ^ (r & 7)) << 3);       // inverse-swizzled k-elem
            const size_t go = (size_t)r * DM + c;
            GLOAD16(a_g + go, lds + (b >> 1));
            GLOAD16(b_g + go, lds + 8192 + (b >> 1));
        }
        __syncthreads();

        #pragma unroll
        for (int ks = 0; ks < 2; ++ks) {
            const int sl = (ks << 2) | kc;
            half8 bf[4];
            #pragma unroll
            for (int n = 0; n < 4; ++n) {
                const int row = wc * 64 + n * 16 + fr;
                bf[n] = *(const half8*)(lds + 8192 + row * 64 + ((sl ^ (row & 7)) << 3));
            }
            #pragma unroll
            for (int m = 0; m < 4; ++m) {
                const int row = wr * 64 + m * 16 + fr;
                half8 af = *(const half8*)(lds + row * 64 + ((sl ^ (row & 7)) << 3));
                #pragma unroll
                for (int n = 0; n < 4; ++n)
                    acc[m][n] = __builtin_amdgcn_mfma_f32_16x16x32_f16(af, bf[n], acc[m][n], 0, 0, 0);
            }
        }
        __syncthreads();
    }

    float csum[4] = {0.f, 0.f, 0.f, 0.f};
    #pragma unroll
    for (int m = 0; m < 4; ++m) {
        const int gr0 = row0 + wr * 64 + m * 16 + kc * 4;
        #pragma unroll
        for (int n = 0; n < 4; ++n) {
            const int j = col0 + wc * 64 + n * 16 + fr;
            const float bj = bias[j];
            const int h = j >> 6, dd = j & 63;
            #pragma unroll
            for (int r2 = 0; r2 < 4; ++r2) {
                const int i = gr0 + r2;
                const int nn = i >> 11, l = i & (L_ - 1);
                float v = acc[m][n][r2] + bj;
                if (z < 2) { v = sigmoidf_(v); csum[n] += v; }
                outp[(((size_t)(nn * H_ + h)) * L_ + l) * HD_ + dd] = (_Float16)v;
            }
        }
    }

    if (z < 2) {
        float* scol = (float*)lds;             // LDS free after final barrier
        if (t < 128) scol[t] = 0.f;
        __syncthreads();
        #pragma unroll
        for (int n = 0; n < 4; ++n)
            atomicAdd(&scol[wc * 64 + n * 16 + fr], csum[n]);
        __syncthreads();
        if (t < 128) {
            const int j = col0 + t;
            const int nn = row0 >> 11;
            float* dst = (z == 0) ? qsum : ksum;
            atomicAdd(&dst[(nn * H_ + (j >> 6)) * 64 + (j & 63)], scol[t]);
        }
    }
}

// ===========================================================================
// Output GEMM: single-product f16 (attn @ Woh^T + bo), BK=64, f32 store.
// ===========================================================================
__global__ __launch_bounds__(256) void gemm_out_kernel(
    const _Float16* __restrict__ af, const _Float16* __restrict__ wo,
    const float* __restrict__ bias, float* __restrict__ outp)
{
    __shared__ _Float16 lds[2 * 8192];
    const int row0 = blockIdx.y * 128;
    const int col0 = blockIdx.x * 128;
    const int t = threadIdx.x;
    const int lane = t & 63;
    const int w = t >> 6;
    const int wr = w >> 1, wc = w & 1;
    const int fr = lane & 15, kc = lane >> 4;

    f32x4 acc[4][4];
    #pragma unroll
    for (int m = 0; m < 4; ++m)
        #pragma unroll
        for (int n = 0; n < 4; ++n) acc[m][n] = f32x4{0.f, 0.f, 0.f, 0.f};

    for (int k0 = 0; k0 < DM; k0 += 64) {
        const _Float16* a_g = af + (size_t)row0 * DM + k0;
        const _Float16* b_g = wo + (size_t)col0 * DM + k0;
        #pragma unroll
        for (int p = 0; p < 4; ++p) {
            const int b = p * 4096 + t * 16;
            const int r = b >> 7;
            const int s = (b >> 4) & 7;
            const int c = ((s ^ (r & 7)) << 3);
            const size_t go = (size_t)r * DM + c;
            GLOAD16(a_g + go, lds + (b >> 1));
            GLOAD16(b_g + go, lds + 8192 + (b >> 1));
        }
        __syncthreads();

        #pragma unroll
        for (int ks = 0; ks < 2; ++ks) {
            const int sl = (ks << 2) | kc;
            half8 bf[4];
            #pragma unroll
            for (int n = 0; n < 4; ++n) {
                const int row = wc * 64 + n * 16 + fr;
                bf[n] = *(const half8*)(lds + 8192 + row * 64 + ((sl ^ (row & 7)) << 3));
            }
            #pragma unroll
            for (int m = 0; m < 4; ++m) {
                const int row = wr * 64 + m * 16 + fr;
                half8 af8 = *(const half8*)(lds + row * 64 + ((sl ^ (row & 7)) << 3));
                #pragma unroll
                for (int n = 0; n < 4; ++n)
                    acc[m][n] = __builtin_amdgcn_mfma_f32_16x16x32_f16(af8, bf[n], acc[m][n], 0, 0, 0);
            }
        }
        __syncthreads();
    }

    #pragma unroll
    for (int m = 0; m < 4; ++m) {
        const int gr0 = row0 + wr * 64 + m * 16 + kc * 4;
        #pragma unroll
        for (int n = 0; n < 4; ++n) {
            const int j = col0 + wc * 64 + n * 16 + fr;
            const float bj = bias[j];
            #pragma unroll
            for (int r2 = 0; r2 < 4; ++r2)
                outp[(size_t)(gr0 + r2) * DM + j] = acc[m][n][r2] + bj;
        }
    }
}

// ---------------------------------------------------------------------------
// stage1: per l compute si (stored) and so (inline); atomicAdd qsi/kso.
// q,k are f16 now (half the read traffic).
// ---------------------------------------------------------------------------
__global__ __launch_bounds__(256) void stage1_part_kernel(
    const _Float16* __restrict__ q, const _Float16* __restrict__ k,
    const float* __restrict__ qsum, const float* __restrict__ ksum,
    float* __restrict__ si, float* __restrict__ qsi, float* __restrict__ kso)
{
    const int nh = blockIdx.x, ch = blockIdx.y;
    const _Float16* qp = q + (size_t)nh * L_ * HD_;
    const _Float16* kp = k + (size_t)nh * L_ * HD_;
    const int lane = threadIdx.x & 63;
    const int w = threadIdx.x >> 6;
    const float ksv = ksum[nh * 64 + lane] + EPS_;
    const float qsv = qsum[nh * 64 + lane] + EPS_;
    float qsi_acc = 0.f, kso_acc = 0.f;
    for (int l = ch * 128 + w; l < (ch + 1) * 128; l += 4) {
        const float qv = (float)qp[(size_t)l * HD_ + lane];
        const float kv = (float)kp[(size_t)l * HD_ + lane];
        float a = (qv + EPS_) * ksv;
        float b = (kv + EPS_) * qsv;
        #pragma unroll
        for (int off = 32; off >= 1; off >>= 1) {
            a += __shfl_xor(a, off, 64);
            b += __shfl_xor(b, off, 64);
        }
        const float siv = 1.f / a;
        const float sov = 1.f / b;
        if (lane == 0) si[nh * L_ + l] = siv;
        qsi_acc += qv * siv;
        kso_acc += kv * sov;
    }
    __shared__ float s1[4][64], s2[4][64];
    s1[w][lane] = qsi_acc; s2[w][lane] = kso_acc;
    __syncthreads();
    if (w == 0) {
        atomicAdd(&qsi[nh * 64 + lane], s1[0][lane] + s1[1][lane] + s1[2][lane] + s1[3][lane]);
        atomicAdd(&kso[nh * 64 + lane], s2[0][lane] + s2[1][lane] + s2[2][lane] + s2[3][lane]);
    }
}

// ---------------------------------------------------------------------------
// kv partial over 256-l chunk with fused source-competition; k,v f16 input.
// LDS staged as padded f32 [32][65] (2-way free), half8 vector global loads.
// ---------------------------------------------------------------------------
__global__ __launch_bounds__(256) void kv_part_kernel(
    const _Float16* __restrict__ k, const _Float16* __restrict__ v,
    const float* __restrict__ qsi, float* __restrict__ kvp, float* __restrict__ psum_p)
{
    const int nh = blockIdx.x, ch = blockIdx.y;
    const _Float16* kp = k + (size_t)nh * L_ * HD_;
    const _Float16* vp = v + (size_t)nh * L_ * HD_;
    const int lane = threadIdx.x & 63;
    const int w = threadIdx.x >> 6;
    const float qsiv = qsi[nh * 64 + lane] + EPS_;

    float acc[16] = {0.f};
    float psum = 0.f;
    __shared__ float ks[32][65], vs[32][65];
    __shared__ float pl[32];
    for (int l0 = ch * 256; l0 < (ch + 1) * 256; l0 += 32) {
        {
            const half8* kp8 = (const half8*)(kp + (size_t)l0 * HD_);
            const half8* vp8 = (const half8*)(vp + (size_t)l0 * HD_);
            half8 k8 = kp8[threadIdx.x];
            half8 v8 = vp8[threadIdx.x];
            const int r = threadIdx.x >> 3, c = (threadIdx.x & 7) * 8;
            #pragma unroll
            for (int j = 0; j < 8; ++j) {
                ks[r][c + j] = (float)k8[j];
                vs[r][c + j] = (float)v8[j];
            }
        }
        __syncthreads();
        #pragma unroll
        for (int ll = w * 8; ll < w * 8 + 8; ++ll) {
            float b = (ks[ll][lane] + EPS_) * qsiv;
            #pragma unroll
            for (int off = 32; off >= 1; off >>= 1) b += __shfl_xor(b, off, 64);
            b = fminf(1.f, fmaxf(-1.f, b));
            const float p = expf(b);
            if (lane == 0) pl[ll] = p;
            psum += p;
        }
        __syncthreads();
        #pragma unroll 4
        for (int ll = 0; ll < 32; ++ll) {
            const float vv = vs[ll][lane] * pl[ll];
            #pragma unroll
            for (int dd = 0; dd < 16; ++dd) acc[dd] += ks[ll][w * 16 + dd] * vv;
        }
        __syncthreads();
    }
    #pragma unroll
    for (int dd = 0; dd < 16; ++dd)
        kvp[((size_t)(nh * 8 + ch) * 64 + (w * 16 + dd)) * 64 + lane] = acc[dd];

    __shared__ float sp[4];
    if (lane == 0) sp[w] = psum;
    __syncthreads();
    if (threadIdx.x == 0) psum_p[nh * 8 + ch] = sp[0] + sp[1] + sp[2] + sp[3];
}

// reduce kv partials and apply deferred softmax scale L/tot
__global__ __launch_bounds__(256) void kv_reduce_kernel(
    const float* __restrict__ kvp, const float* __restrict__ psum_p,
    float* __restrict__ kvb)
{
    const int nh = blockIdx.x;
    float tot = 0.f;
    #pragma unroll
    for (int c = 0; c < 8; ++c) tot += psum_p[nh * 8 + c];
    const float scale = (float)L_ / tot;
    for (int e = threadIdx.x; e < 4096; e += 256) {
        float s = 0.f;
        #pragma unroll
        for (int c = 0; c < 8; ++c) s += kvp[(size_t)(nh * 8 + c) * 4096 + e];
        kvb[(size_t)nh * 4096 + e] = s * scale;
    }
}

// ---------------------------------------------------------------------------
// out with fused sink_allocation; q f16 input (padded f32 LDS), f16 attn store
// ---------------------------------------------------------------------------
__global__ __launch_bounds__(256) void out_kernel(
    const _Float16* __restrict__ q, const float* __restrict__ kvb,
    const float* __restrict__ si, const float* __restrict__ kso,
    _Float16* __restrict__ attn_f)
{
    const int nh = blockIdx.x;
    const int n = nh >> 4;
    const int h = nh & 15;
    const int l0 = blockIdx.y * 64;
    __shared__ float kvs[64][64];
    __shared__ float qs[64][65];
    __shared__ float sal[64];
    for (int i = threadIdx.x; i < 4096; i += 256)
        kvs[i >> 6][i & 63] = kvb[(size_t)nh * 4096 + i];
    {
        const half8* src8 = (const half8*)(q + ((size_t)nh * L_ + l0) * HD_);
        for (int i = threadIdx.x; i < 512; i += 256) {
            half8 v8 = src8[i];
            const int r = i >> 3, c = (i & 7) * 8;
            #pragma unroll
            for (int j = 0; j < 8; ++j) qs[r][c + j] = (float)v8[j];
        }
    }
    __syncthreads();
    const int lane = threadIdx.x & 63;
    const int w = threadIdx.x >> 6;
    const float ksov = kso[nh * 64 + lane] + EPS_;
    for (int ll = w; ll < 64; ll += 4) {
        float a = (qs[ll][lane] + EPS_) * ksov;
        #pragma unroll
        for (int off = 32; off >= 1; off >>= 1) a += __shfl_xor(a, off, 64);
        if (lane == 0) sal[ll] = sigmoidf_(a);
    }
    __syncthreads();
    for (int ll = w; ll < 64; ll += 4) {
        const int l = l0 + ll;
        float acc = 0.f;
        #pragma unroll
        for (int d = 0; d < 64; ++d) acc += qs[ll][d] * kvs[d][lane];
        const float val = acc * si[nh * L_ + l] * sal[ll];
        attn_f[((size_t)n * L_ + l) * DM + h * 64 + lane] = (_Float16)val;
    }
}

extern "C" void kernel_launch(void* const* d_in, const int* in_sizes, int n_in,
                              void* d_out, int out_size, void* d_ws, size_t ws_size,
                              hipStream_t stream)
{
    const float* x  = (const float*)d_in[0];
    const float* Wq = (const float*)d_in[1];
    const float* bq = (const float*)d_in[2];
    const float* Wk = (const float*)d_in[3];
    const float* bk = (const float*)d_in[4];
    const float* Wv = (const float*)d_in[5];
    const float* bv = (const float*)d_in[6];
    const float* Wo = (const float*)d_in[7];
    const float* bo = (const float*)d_in[8];
    float* out = (float*)d_out;

    float* ws = (float*)d_ws;
    size_t off = 0;
    const size_t big = (size_t)B_ * L_ * DM;   // 8,388,608 elems
    // q,k,v f16 planes (big f16 = big/2 float slots each)
    _Float16* qbuf = (_Float16*)(ws + off); off += big / 2;
    _Float16* kbuf = (_Float16*)(ws + off); off += big / 2;
    _Float16* vbuf = (_Float16*)(ws + off); off += big / 2;
    // union region: x f16 during projections, attn f16 afterwards
    _Float16* xf = (_Float16*)(ws + off);
    _Float16* attn_f = xf;
    off += big / 2;
    _Float16* wh3 = (_Float16*)(ws + off); off += (size_t)3 * DM * DM / 2;
    _Float16* woh = (_Float16*)(ws + off); off += (size_t)DM * DM / 2;
    float* kvp    = ws + off; off += (size_t)NH_ * 8 * 64 * 64;
    float* kvb    = ws + off; off += (size_t)NH_ * 64 * 64;
    float* sums = ws + off;
    float* qsum = sums;
    float* ksum = sums + 1 * NH_ * 64;
    float* qsi  = sums + 2 * NH_ * 64;
    float* kso  = sums + 3 * NH_ * 64;
    off += 4 * NH_ * 64;
    float* psum_p = ws + off; off += NH_ * 8;
    float* si     = ws + off; off += NH_ * L_;

    // 0. zero the atomic accumulators
    zero_kernel<<<(4 * NH_ * 64 + 255) / 256, 256, 0, stream>>>(sums, 4 * NH_ * 64);

    // 1. x -> f16; all weights -> f16 hi
    splitx_kernel<<<big / 4 / 256, 256, 0, stream>>>(x, xf, (int)(big / 4));
    split_w4_kernel<<<dim3(DM * DM / 4 / 256, 4), 256, 0, stream>>>(
        Wq, Wk, Wv, Wo, wh3, woh);

    // 2. QKV projection GEMMs (single-product f16, BK=64) + fused colsum,
    //    f16 q/k/v stores
    dim3 gqkv(DM / 128, (B_ * L_) / 128, 3);
    gemm_qkv_kernel<<<gqkv, 256, 0, stream>>>(xf, wh3, bq, bk, bv,
                                              qbuf, kbuf, vbuf, qsum, ksum);

    // 3. stage1 (si + qsi/kso atomics), f16 reads
    stage1_part_kernel<<<dim3(NH_, 16), 256, 0, stream>>>(qbuf, kbuf, qsum, ksum, si, qsi, kso);

    // 4. kv with fused source-competition (f16 reads); deferred scale in reduce
    kv_part_kernel<<<dim3(NH_, 8), 256, 0, stream>>>(kbuf, vbuf, qsi, kvp, psum_p);
    kv_reduce_kernel<<<NH_, 256, 0, stream>>>(kvp, psum_p, kvb);

    // 5. out with fused sink_allocation (f16 q read) -> f16 attn
    out_kernel<<<dim3(NH_, L_ / 64), 256, 0, stream>>>(qbuf, kvb, si, kso, attn_f);

    // 6. output projection GEMM (single-product f16, BK=64)
    dim3 gout(DM / 128, (B_ * L_) / 128);
    gemm_out_kernel<<<gout, 256, 0, stream>>>(attn_f, woh, bo, out);
}

// Round 12
// 240.098 us; speedup vs baseline: 1.8063x; 1.2445x over previous
//
#include <hip/hip_runtime.h>
#include <math.h>

#define B_ 4
#define L_ 2048
#define DM 1024
#define H_ 16
#define HD_ 64
#define NH_ 64            // B_*H_
#define EPS_ 1e-6f

typedef float f32x4 __attribute__((ext_vector_type(4)));
typedef _Float16 half8 __attribute__((ext_vector_type(8)));
typedef _Float16 half4 __attribute__((ext_vector_type(4)));

typedef __attribute__((address_space(3))) void lds_v;
typedef const __attribute__((address_space(1))) void glb_v;
#define GLOAD16(g, l) __builtin_amdgcn_global_load_lds((glb_v*)(g), (lds_v*)(l), 16, 0, 0)

__device__ __forceinline__ float sigmoidf_(float x) { return 1.0f / (1.0f + expf(-x)); }

// ---------------------------------------------------------------------------
// x -> f16 (RNE)
// ---------------------------------------------------------------------------
__global__ __launch_bounds__(256) void splitx_kernel(
    const float* __restrict__ in, _Float16* __restrict__ outp, int n4)
{
    const int i = blockIdx.x * 256 + threadIdx.x;
    if (i >= n4) return;
    f32x4 v = *(const f32x4*)(in + (size_t)i * 4);
    half4 h = { (_Float16)v[0], (_Float16)v[1], (_Float16)v[2], (_Float16)v[3] };
    *(half4*)(outp + (size_t)i * 4) = h;
}

// all 4 weights -> f16; also zero the atomic accumulator block (y==0 lane)
__global__ __launch_bounds__(256) void split_w4_kernel(
    const float* __restrict__ Wq, const float* __restrict__ Wk,
    const float* __restrict__ Wv, const float* __restrict__ Wo,
    _Float16* __restrict__ wh3, _Float16* __restrict__ woh,
    float* __restrict__ sums)
{
    const int y = blockIdx.y;
    if (y == 0 && blockIdx.x < 64)
        sums[blockIdx.x * 256 + threadIdx.x] = 0.f;   // 64*256 = 16384 floats
    const float* src = (y == 0) ? Wq : (y == 1) ? Wk : (y == 2) ? Wv : Wo;
    _Float16* hh = (y < 3) ? (wh3 + (size_t)y * DM * DM) : woh;
    const int i = blockIdx.x * 256 + threadIdx.x;   // i < DM*DM/4
    f32x4 v = *(const f32x4*)(src + (size_t)i * 4);
    half4 h = { (_Float16)v[0], (_Float16)v[1], (_Float16)v[2], (_Float16)v[3] };
    *(half4*)(hh + (size_t)i * 4) = h;
}

// ===========================================================================
// QKV GEMM: single-product f16, BK=64, m97 structure + XCD-swizzled 1D grid.
//   1536 blocks = 8 XCDs x 192; orig id = z*512 + by*8 + bx.
//   Epilogue: +bias, sigmoid q/k, scatter [B,H,L,HD] f16, fused colsum.
// ===========================================================================
__global__ __launch_bounds__(256) void gemm_qkv_kernel(
    const _Float16* __restrict__ xf,
    const _Float16* __restrict__ wh,                               // [3][DM][DM]
    const float* __restrict__ bq, const float* __restrict__ bk, const float* __restrict__ bv,
    _Float16* __restrict__ qb, _Float16* __restrict__ kb, _Float16* __restrict__ vb,
    float* __restrict__ qsum, float* __restrict__ ksum)
{
    const int bid = (int)blockIdx.x;
    const int wg = (bid & 7) * 192 + (bid >> 3);   // bijective, 1536 % 8 == 0
    const int z = wg / 512;
    const int rem = wg & 511;
    const int row0 = (rem >> 3) * 128;
    const int col0 = (rem & 7) * 128;
    const float* __restrict__ bias  = (z == 0) ? bq : (z == 1) ? bk : bv;
    _Float16* __restrict__ outp     = (z == 0) ? qb : (z == 1) ? kb : vb;
    const _Float16* Wh = wh + (size_t)z * DM * DM;

    __shared__ _Float16 lds[2 * 8192];   // A plane | B plane, 16 KB each
    const int t = threadIdx.x;
    const int lane = t & 63;
    const int w = t >> 6;
    const int wr = w >> 1, wc = w & 1;
    const int fr = lane & 15, kc = lane >> 4;

    f32x4 acc[4][4];
    #pragma unroll
    for (int m = 0; m < 4; ++m)
        #pragma unroll
        for (int n = 0; n < 4; ++n) acc[m][n] = f32x4{0.f, 0.f, 0.f, 0.f};

    for (int k0 = 0; k0 < DM; k0 += 64) {
        const _Float16* a_g = xf + (size_t)row0 * DM + k0;
        const _Float16* b_g = Wh + (size_t)col0 * DM + k0;
        #pragma unroll
        for (int p = 0; p < 4; ++p) {
            const int b = p * 4096 + t * 16;          // byte in 16 KB plane
            const int r = b >> 7;                     // row 0..127
            const int s = (b >> 4) & 7;               // 16B slot in 128B row
            const int c = ((s ^ (r & 7)) << 3);       // inverse-swizzled k-elem
            const size_t go = (size_t)r * DM + c;
            GLOAD16(a_g + go, lds + (b >> 1));
            GLOAD16(b_g + go, lds + 8192 + (b >> 1));
        }
        __syncthreads();

        #pragma unroll
        for (int ks = 0; ks < 2; ++ks) {
            const int sl = (ks << 2) | kc;
            half8 bf[4];
            #pragma unroll
            for (int n = 0; n < 4; ++n) {
                const int row = wc * 64 + n * 16 + fr;
                bf[n] = *(const half8*)(lds + 8192 + row * 64 + ((sl ^ (row & 7)) << 3));
            }
            #pragma unroll
            for (int m = 0; m < 4; ++m) {
                const int row = wr * 64 + m * 16 + fr;
                half8 af = *(const half8*)(lds + row * 64 + ((sl ^ (row & 7)) << 3));
                #pragma unroll
                for (int n = 0; n < 4; ++n)
                    acc[m][n] = __builtin_amdgcn_mfma_f32_16x16x32_f16(af, bf[n], acc[m][n], 0, 0, 0);
            }
        }
        __syncthreads();
    }

    float csum[4] = {0.f, 0.f, 0.f, 0.f};
    #pragma unroll
    for (int m = 0; m < 4; ++m) {
        const int gr0 = row0 + wr * 64 + m * 16 + kc * 4;
        #pragma unroll
        for (int n = 0; n < 4; ++n) {
            const int j = col0 + wc * 64 + n * 16 + fr;
            const float bj = bias[j];
            const int h = j >> 6, dd = j & 63;
            #pragma unroll
            for (int r2 = 0; r2 < 4; ++r2) {
                const int i = gr0 + r2;
                const int nn = i >> 11, l = i & (L_ - 1);
                float v = acc[m][n][r2] + bj;
                if (z < 2) { v = sigmoidf_(v); csum[n] += v; }
                outp[(((size_t)(nn * H_ + h)) * L_ + l) * HD_ + dd] = (_Float16)v;
            }
        }
    }

    if (z < 2) {
        float* scol = (float*)lds;             // LDS free after final barrier
        if (t < 128) scol[t] = 0.f;
        __syncthreads();
        #pragma unroll
        for (int n = 0; n < 4; ++n)
            atomicAdd(&scol[wc * 64 + n * 16 + fr], csum[n]);
        __syncthreads();
        if (t < 128) {
            const int j = col0 + t;
            const int nn = row0 >> 11;
            float* dst = (z == 0) ? qsum : ksum;
            atomicAdd(&dst[(nn * H_ + (j >> 6)) * 64 + (j & 63)], scol[t]);
        }
    }
}

// ===========================================================================
// Output GEMM: single-product f16, BK=64, XCD-swizzled 1D grid (512 = 8x64).
// ===========================================================================
__global__ __launch_bounds__(256) void gemm_out_kernel(
    const _Float16* __restrict__ af, const _Float16* __restrict__ wo,
    const float* __restrict__ bias, float* __restrict__ outp)
{
    const int bid = (int)blockIdx.x;
    const int wg = (bid & 7) * 64 + (bid >> 3);
    const int row0 = (wg >> 3) * 128;
    const int col0 = (wg & 7) * 128;

    __shared__ _Float16 lds[2 * 8192];
    const int t = threadIdx.x;
    const int lane = t & 63;
    const int w = t >> 6;
    const int wr = w >> 1, wc = w & 1;
    const int fr = lane & 15, kc = lane >> 4;

    f32x4 acc[4][4];
    #pragma unroll
    for (int m = 0; m < 4; ++m)
        #pragma unroll
        for (int n = 0; n < 4; ++n) acc[m][n] = f32x4{0.f, 0.f, 0.f, 0.f};

    for (int k0 = 0; k0 < DM; k0 += 64) {
        const _Float16* a_g = af + (size_t)row0 * DM + k0;
        const _Float16* b_g = wo + (size_t)col0 * DM + k0;
        #pragma unroll
        for (int p = 0; p < 4; ++p) {
            const int b = p * 4096 + t * 16;
            const int r = b >> 7;
            const int s = (b >> 4) & 7;
            const int c = ((s ^ (r & 7)) << 3);
            const size_t go = (size_t)r * DM + c;
            GLOAD16(a_g + go, lds + (b >> 1));
            GLOAD16(b_g + go, lds + 8192 + (b >> 1));
        }
        __syncthreads();

        #pragma unroll
        for (int ks = 0; ks < 2; ++ks) {
            const int sl = (ks << 2) | kc;
            half8 bf[4];
            #pragma unroll
            for (int n = 0; n < 4; ++n) {
                const int row = wc * 64 + n * 16 + fr;
                bf[n] = *(const half8*)(lds + 8192 + row * 64 + ((sl ^ (row & 7)) << 3));
            }
            #pragma unroll
            for (int m = 0; m < 4; ++m) {
                const int row = wr * 64 + m * 16 + fr;
                half8 af8 = *(const half8*)(lds + row * 64 + ((sl ^ (row & 7)) << 3));
                #pragma unroll
                for (int n = 0; n < 4; ++n)
                    acc[m][n] = __builtin_amdgcn_mfma_f32_16x16x32_f16(af8, bf[n], acc[m][n], 0, 0, 0);
            }
        }
        __syncthreads();
    }

    #pragma unroll
    for (int m = 0; m < 4; ++m) {
        const int gr0 = row0 + wr * 64 + m * 16 + kc * 4;
        #pragma unroll
        for (int n = 0; n < 4; ++n) {
            const int j = col0 + wc * 64 + n * 16 + fr;
            const float bj = bias[j];
            #pragma unroll
            for (int r2 = 0; r2 < 4; ++r2)
                outp[(size_t)(gr0 + r2) * DM + j] = acc[m][n][r2] + bj;
        }
    }
}

// ---------------------------------------------------------------------------
// stage1 v2 — rowgroup-8 dots, no per-row wave-wide shuffles.
//   Thread (r8 = lane>>3, oct = lane&7): 8 lanes per row, each dots 8 d's
//   against LDS-broadcast sums; 3-step xor reduce within octet; si stored;
//   qsi/kso accumulated per-lane (8 d-slots) and cross-reduced once at end.
//   Grid (NH, 8) x 256 thr; 256 rows per block, 8 iterations of 32 rows.
// ---------------------------------------------------------------------------
__global__ __launch_bounds__(256) void stage1_kernel(
    const _Float16* __restrict__ q, const _Float16* __restrict__ k,
    const float* __restrict__ qsum, const float* __restrict__ ksum,
    float* __restrict__ si, float* __restrict__ qsi, float* __restrict__ kso)
{
    const int nh = blockIdx.x, ch = blockIdx.y;
    const _Float16* qp = q + (size_t)nh * L_ * HD_;
    const _Float16* kp = k + (size_t)nh * L_ * HD_;
    const int tid = threadIdx.x;
    const int lane = tid & 63;
    const int w = tid >> 6;
    const int r8 = lane >> 3;     // 0..7 (row within wave-iter)
    const int oct = lane & 7;     // 0..7 (d-octant)

    __shared__ float ksum_s[64], qsum_s[64];
    __shared__ float s1[4][64], s2[4][64];
    if (tid < 64) {
        ksum_s[tid] = ksum[nh * 64 + tid] + EPS_;
        qsum_s[tid] = qsum[nh * 64 + tid] + EPS_;
    }
    __syncthreads();

    float qacc[8] = {0.f}, kacc[8] = {0.f};
    #pragma unroll
    for (int it = 0; it < 8; ++it) {
        const int l = ch * 256 + it * 32 + w * 8 + r8;
        half8 q8 = *(const half8*)(qp + (size_t)l * HD_ + oct * 8);
        half8 k8 = *(const half8*)(kp + (size_t)l * HD_ + oct * 8);
        float a = 0.f, b = 0.f;
        #pragma unroll
        for (int j = 0; j < 8; ++j) {
            a += ((float)q8[j] + EPS_) * ksum_s[oct * 8 + j];
            b += ((float)k8[j] + EPS_) * qsum_s[oct * 8 + j];
        }
        a += __shfl_xor(a, 1); a += __shfl_xor(a, 2); a += __shfl_xor(a, 4);
        b += __shfl_xor(b, 1); b += __shfl_xor(b, 2); b += __shfl_xor(b, 4);
        const float siv = 1.f / a;
        const float sov = 1.f / b;
        if (oct == 0) si[nh * L_ + l] = siv;
        #pragma unroll
        for (int j = 0; j < 8; ++j) {
            qacc[j] += (float)q8[j] * siv;
            kacc[j] += (float)k8[j] * sov;
        }
    }
    // reduce across the 8 row-groups (bits 3..5 of lane)
    #pragma unroll
    for (int j = 0; j < 8; ++j) {
        qacc[j] += __shfl_xor(qacc[j], 8);  qacc[j] += __shfl_xor(qacc[j], 16); qacc[j] += __shfl_xor(qacc[j], 32);
        kacc[j] += __shfl_xor(kacc[j], 8);  kacc[j] += __shfl_xor(kacc[j], 16); kacc[j] += __shfl_xor(kacc[j], 32);
    }
    if (r8 == 0) {
        #pragma unroll
        for (int j = 0; j < 8; ++j) { s1[w][oct * 8 + j] = qacc[j]; s2[w][oct * 8 + j] = kacc[j]; }
    }
    __syncthreads();
    if (tid < 64) {
        atomicAdd(&qsi[nh * 64 + tid], s1[0][tid] + s1[1][tid] + s1[2][tid] + s1[3][tid]);
        atomicAdd(&kso[nh * 64 + tid], s2[0][tid] + s2[1][tid] + s2[2][tid] + s2[3][tid]);
    }
}

// ---------------------------------------------------------------------------
// kv partial with fused source-competition; p via rowgroup-8 dots on the
// staged LDS tile (3 shfl) instead of wave-serial 6-shfl chains.
// ---------------------------------------------------------------------------
__global__ __launch_bounds__(256) void kv_part_kernel(
    const _Float16* __restrict__ k, const _Float16* __restrict__ v,
    const float* __restrict__ qsi, float* __restrict__ kvp, float* __restrict__ psum_p)
{
    const int nh = blockIdx.x, ch = blockIdx.y;
    const _Float16* kp = k + (size_t)nh * L_ * HD_;
    const _Float16* vp = v + (size_t)nh * L_ * HD_;
    const int tid = threadIdx.x;
    const int lane = tid & 63;
    const int w = tid >> 6;
    const int row8 = tid >> 3;    // 0..31 (row for p-computation)
    const int oct = tid & 7;

    __shared__ float qsi_s[64];
    __shared__ float ks[32][65], vs[32][65];
    __shared__ float pl[32];
    if (tid < 64) qsi_s[tid] = qsi[nh * 64 + tid] + EPS_;
    __syncthreads();

    float acc[16] = {0.f};
    float psum_acc = 0.f;
    for (int l0 = ch * 256; l0 < (ch + 1) * 256; l0 += 32) {
        {
            const half8* kp8 = (const half8*)(kp + (size_t)l0 * HD_);
            const half8* vp8 = (const half8*)(vp + (size_t)l0 * HD_);
            half8 k8 = kp8[tid];
            half8 v8 = vp8[tid];
            const int r = tid >> 3, c = (tid & 7) * 8;
            #pragma unroll
            for (int j = 0; j < 8; ++j) {
                ks[r][c + j] = (float)k8[j];
                vs[r][c + j] = (float)v8[j];
            }
        }
        __syncthreads();
        // p for the 32 rows: thread (row8, oct) partial-dots 8 d's, 3-shfl
        {
            float b = 0.f;
            #pragma unroll
            for (int j = 0; j < 8; ++j)
                b += (ks[row8][oct * 8 + j] + EPS_) * qsi_s[oct * 8 + j];
            b += __shfl_xor(b, 1); b += __shfl_xor(b, 2); b += __shfl_xor(b, 4);
            b = fminf(1.f, fmaxf(-1.f, b));
            const float p = expf(b);
            if (oct == 0) { pl[row8] = p; psum_acc += p; }
        }
        __syncthreads();
        #pragma unroll 4
        for (int ll = 0; ll < 32; ++ll) {
            const float vv = vs[ll][lane] * pl[ll];
            #pragma unroll
            for (int dd = 0; dd < 16; ++dd) acc[dd] += ks[ll][w * 16 + dd] * vv;
        }
        __syncthreads();
    }
    #pragma unroll
    for (int dd = 0; dd < 16; ++dd)
        kvp[((size_t)(nh * 8 + ch) * 64 + (w * 16 + dd)) * 64 + lane] = acc[dd];

    // psum: only oct==0 lanes hold contributions; xor 8/16/32 sums them
    psum_acc += __shfl_xor(psum_acc, 8);
    psum_acc += __shfl_xor(psum_acc, 16);
    psum_acc += __shfl_xor(psum_acc, 32);
    psum_acc += __shfl_xor(psum_acc, 1);
    psum_acc += __shfl_xor(psum_acc, 2);
    psum_acc += __shfl_xor(psum_acc, 4);
    __shared__ float sp[4];
    if (lane == 0) sp[w] = psum_acc;
    __syncthreads();
    if (tid == 0) psum_p[nh * 8 + ch] = sp[0] + sp[1] + sp[2] + sp[3];
}

// reduce kv partials and apply deferred softmax scale L/tot
__global__ __launch_bounds__(256) void kv_reduce_kernel(
    const float* __restrict__ kvp, const float* __restrict__ psum_p,
    float* __restrict__ kvb)
{
    const int nh = blockIdx.x;
    float tot = 0.f;
    #pragma unroll
    for (int c = 0; c < 8; ++c) tot += psum_p[nh * 8 + c];
    const float scale = (float)L_ / tot;
    for (int e = threadIdx.x; e < 4096; e += 256) {
        float s = 0.f;
        #pragma unroll
        for (int c = 0; c < 8; ++c) s += kvp[(size_t)(nh * 8 + c) * 4096 + e];
        kvb[(size_t)nh * 4096 + e] = s * scale;
    }
}

// ---------------------------------------------------------------------------
// out with fused sink_allocation; q f16 input (padded f32 LDS), f16 attn store
// ---------------------------------------------------------------------------
__global__ __launch_bounds__(256) void out_kernel(
    const _Float16* __restrict__ q, const float* __restrict__ kvb,
    const float* __restrict__ si, const float* __restrict__ kso,
    _Float16* __restrict__ attn_f)
{
    const int nh = blockIdx.x;
    const int n = nh >> 4;
    const int h = nh & 15;
    const int l0 = blockIdx.y * 64;
    __shared__ float kvs[64][64];
    __shared__ float qs[64][65];
    __shared__ float sal[64];
    __shared__ float kso_s[64];
    const int tid = threadIdx.x;
    for (int i = tid; i < 4096; i += 256)
        kvs[i >> 6][i & 63] = kvb[(size_t)nh * 4096 + i];
    {
        const half8* src8 = (const half8*)(q + ((size_t)nh * L_ + l0) * HD_);
        for (int i = tid; i < 512; i += 256) {
            half8 v8 = src8[i];
            const int r = i >> 3, c = (i & 7) * 8;
            #pragma unroll
            for (int j = 0; j < 8; ++j) qs[r][c + j] = (float)v8[j];
        }
    }
    if (tid < 64) kso_s[tid] = kso[nh * 64 + tid] + EPS_;
    __syncthreads();
    // sink_allocation via rowgroup-8 dots: thread (row= tid>>3 (0..31) + 32*half)
    {
        const int row = tid >> 3;           // 0..31
        const int oct = tid & 7;
        #pragma unroll
        for (int rr = 0; rr < 2; ++rr) {
            const int r = rr * 32 + row;
            float a = 0.f;
            #pragma unroll
            for (int j = 0; j < 8; ++j)
                a += (qs[r][oct * 8 + j] + EPS_) * kso_s[oct * 8 + j];
            a += __shfl_xor(a, 1); a += __shfl_xor(a, 2); a += __shfl_xor(a, 4);
            if (oct == 0) sal[r] = sigmoidf_(a);
        }
    }
    __syncthreads();
    const int lane = tid & 63;
    const int w = tid >> 6;
    for (int ll = w; ll < 64; ll += 4) {
        const int l = l0 + ll;
        float acc = 0.f;
        #pragma unroll
        for (int d = 0; d < 64; ++d) acc += qs[ll][d] * kvs[d][lane];
        const float val = acc * si[nh * L_ + l] * sal[ll];
        attn_f[((size_t)n * L_ + l) * DM + h * 64 + lane] = (_Float16)val;
    }
}

extern "C" void kernel_launch(void* const* d_in, const int* in_sizes, int n_in,
                              void* d_out, int out_size, void* d_ws, size_t ws_size,
                              hipStream_t stream)
{
    const float* x  = (const float*)d_in[0];
    const float* Wq = (const float*)d_in[1];
    const float* bq = (const float*)d_in[2];
    const float* Wk = (const float*)d_in[3];
    const float* bk = (const float*)d_in[4];
    const float* Wv = (const float*)d_in[5];
    const float* bv = (const float*)d_in[6];
    const float* Wo = (const float*)d_in[7];
    const float* bo = (const float*)d_in[8];
    float* out = (float*)d_out;

    float* ws = (float*)d_ws;
    size_t off = 0;
    const size_t big = (size_t)B_ * L_ * DM;   // 8,388,608 elems
    _Float16* qbuf = (_Float16*)(ws + off); off += big / 2;
    _Float16* kbuf = (_Float16*)(ws + off); off += big / 2;
    _Float16* vbuf = (_Float16*)(ws + off); off += big / 2;
    _Float16* xf = (_Float16*)(ws + off);
    _Float16* attn_f = xf;
    off += big / 2;
    _Float16* wh3 = (_Float16*)(ws + off); off += (size_t)3 * DM * DM / 2;
    _Float16* woh = (_Float16*)(ws + off); off += (size_t)DM * DM / 2;
    float* kvp    = ws + off; off += (size_t)NH_ * 8 * 64 * 64;
    float* kvb    = ws + off; off += (size_t)NH_ * 64 * 64;
    float* sums = ws + off;
    float* qsum = sums;
    float* ksum = sums + 1 * NH_ * 64;
    float* qsi  = sums + 2 * NH_ * 64;
    float* kso  = sums + 3 * NH_ * 64;
    off += 4 * NH_ * 64;
    float* psum_p = ws + off; off += NH_ * 8;
    float* si     = ws + off; off += NH_ * L_;

    // 1. x -> f16; all weights -> f16 (also zeroes the accumulator block)
    splitx_kernel<<<big / 4 / 256, 256, 0, stream>>>(x, xf, (int)(big / 4));
    split_w4_kernel<<<dim3(DM * DM / 4 / 256, 4), 256, 0, stream>>>(
        Wq, Wk, Wv, Wo, wh3, woh, sums);

    // 2. QKV projection GEMMs (single-product f16, BK=64, XCD swizzle)
    gemm_qkv_kernel<<<1536, 256, 0, stream>>>(xf, wh3, bq, bk, bv,
                                              qbuf, kbuf, vbuf, qsum, ksum);

    // 3. stage1 v2 (rowgroup dots; si + qsi/kso atomics)
    stage1_kernel<<<dim3(NH_, 8), 256, 0, stream>>>(qbuf, kbuf, qsum, ksum, si, qsi, kso);

    // 4. kv with fused source-competition (rowgroup p-dots)
    kv_part_kernel<<<dim3(NH_, 8), 256, 0, stream>>>(kbuf, vbuf, qsi, kvp, psum_p);
    kv_reduce_kernel<<<NH_, 256, 0, stream>>>(kvp, psum_p, kvb);

    // 5. out with fused sink_allocation (rowgroup dots) -> f16 attn
    out_kernel<<<dim3(NH_, L_ / 64), 256, 0, stream>>>(qbuf, kvb, si, kso, attn_f);

    // 6. output projection GEMM (single-product f16, BK=64, XCD swizzle)
    gemm_out_kernel<<<512, 256, 0, stream>>>(attn_f, woh, bo, out);
}

// Round 13
// 227.681 us; speedup vs baseline: 1.9048x; 1.0545x over previous
//
#include <hip/hip_runtime.h>
#include <math.h>

#define B_ 4
#define L_ 2048
#define DM 1024
#define H_ 16
#define HD_ 64
#define NH_ 64            // B_*H_
#define EPS_ 1e-6f

typedef float f32x4 __attribute__((ext_vector_type(4)));
typedef _Float16 half8 __attribute__((ext_vector_type(8)));
typedef _Float16 half4 __attribute__((ext_vector_type(4)));

typedef __attribute__((address_space(3))) void lds_v;
typedef const __attribute__((address_space(1))) void glb_v;
#define GLOAD16(g, l) __builtin_amdgcn_global_load_lds((glb_v*)(g), (lds_v*)(l), 16, 0, 0)

__device__ __forceinline__ float sigmoidf_(float x) { return 1.0f / (1.0f + expf(-x)); }

// ---------------------------------------------------------------------------
// prep: x -> f16 | weights -> f16 | zero kvb + sums.  One launch.
//   bid < 8192: x chunks (2M half4); bid<1024 also zeroes kvb; bid<64 sums.
//   bid >= 8192: weight chunks, y = (bid-8192)>>10 selects Wq/Wk/Wv/Wo.
// ---------------------------------------------------------------------------
__global__ __launch_bounds__(256) void prep_kernel(
    const float* __restrict__ x,
    const float* __restrict__ Wq, const float* __restrict__ Wk,
    const float* __restrict__ Wv, const float* __restrict__ Wo,
    _Float16* __restrict__ xf, _Float16* __restrict__ wh3, _Float16* __restrict__ woh,
    float* __restrict__ sums, float* __restrict__ kvb)
{
    const int bid = (int)blockIdx.x;
    const int tid = threadIdx.x;
    if (bid < 8192) {
        const int i = bid * 256 + tid;
        f32x4 v = *(const f32x4*)(x + (size_t)i * 4);
        half4 h = { (_Float16)v[0], (_Float16)v[1], (_Float16)v[2], (_Float16)v[3] };
        *(half4*)(xf + (size_t)i * 4) = h;
        if (bid < 1024) kvb[bid * 256 + tid] = 0.f;          // 256K floats
        if (bid < 64)   sums[bid * 256 + tid] = 0.f;         // 16K floats
    } else {
        const int r = bid - 8192;          // 0..4095
        const int y = r >> 10;             // 0..3
        const int i = (r & 1023) * 256 + tid;
        const float* src = (y == 0) ? Wq : (y == 1) ? Wk : (y == 2) ? Wv : Wo;
        _Float16* hh = (y < 3) ? (wh3 + (size_t)y * DM * DM) : woh;
        f32x4 v = *(const f32x4*)(src + (size_t)i * 4);
        half4 h = { (_Float16)v[0], (_Float16)v[1], (_Float16)v[2], (_Float16)v[3] };
        *(half4*)(hh + (size_t)i * 4) = h;
    }
}

// ===========================================================================
// QKV GEMM: single-product f16, BK=64, T3-minimum 2-phase double-buffer.
//   Per K-tile: STAGE(t+1 -> buf^1) issued BEFORE compute(t); ONE
//   __syncthreads() per tile (its vmcnt/lgkm drain completes the prefetch).
//   Buffers disjoint -> race-free.  LDS 2 x (16KB A + 16KB B) = 64 KB.
//   Swizzle: slot' = slot^(row&7) on 16B slots of 128B rows; linear gload
//   dest + inverse-swizzled source k-offset + swizzled ds_read (2-way free).
//   XCD-swizzled 1D grid (1536 = 8 x 192).  Epilogue: +bias, sigmoid q/k,
//   scatter [B,H,L,HD] f16, fused post-sigmoid colsum -> atomicAdd.
// ===========================================================================
__global__ __launch_bounds__(256) void gemm_qkv_kernel(
    const _Float16* __restrict__ xf,
    const _Float16* __restrict__ wh,                               // [3][DM][DM]
    const float* __restrict__ bq, const float* __restrict__ bk, const float* __restrict__ bv,
    _Float16* __restrict__ qb, _Float16* __restrict__ kb, _Float16* __restrict__ vb,
    float* __restrict__ qsum, float* __restrict__ ksum)
{
    const int bid = (int)blockIdx.x;
    const int wg = (bid & 7) * 192 + (bid >> 3);   // bijective, 1536 % 8 == 0
    const int z = wg / 512;
    const int rem = wg & 511;
    const int row0 = (rem >> 3) * 128;
    const int col0 = (rem & 7) * 128;
    const float* __restrict__ bias  = (z == 0) ? bq : (z == 1) ? bk : bv;
    _Float16* __restrict__ outp     = (z == 0) ? qb : (z == 1) ? kb : vb;
    const _Float16* Wh = wh + (size_t)z * DM * DM;

    __shared__ _Float16 lds[2 * 16384];   // dbuf x (A 16KB | B 16KB)
    const int t = threadIdx.x;
    const int lane = t & 63;
    const int w = t >> 6;
    const int wr = w >> 1, wc = w & 1;
    const int fr = lane & 15, kc = lane >> 4;

    auto STAGE = [&](int k0, int buf) {
        const _Float16* a_g = xf + (size_t)row0 * DM + k0;
        const _Float16* b_g = Wh + (size_t)col0 * DM + k0;
        _Float16* dst = lds + buf * 16384;
        #pragma unroll
        for (int p = 0; p < 4; ++p) {
            const int b = p * 4096 + t * 16;          // byte in 16 KB plane
            const int r = b >> 7;                     // row 0..127
            const int s = (b >> 4) & 7;               // 16B slot in 128B row
            const int c = ((s ^ (r & 7)) << 3);       // inverse-swizzled k-elem
            const size_t go = (size_t)r * DM + c;
            GLOAD16(a_g + go, dst + (b >> 1));
            GLOAD16(b_g + go, dst + 8192 + (b >> 1));
        }
    };

    f32x4 acc[4][4];
    #pragma unroll
    for (int m = 0; m < 4; ++m)
        #pragma unroll
        for (int n = 0; n < 4; ++n) acc[m][n] = f32x4{0.f, 0.f, 0.f, 0.f};

    STAGE(0, 0);
    __syncthreads();

    for (int kt = 0; kt < 16; ++kt) {
        if (kt + 1 < 16) STAGE((kt + 1) * 64, (kt + 1) & 1);
        const _Float16* bufA = lds + (kt & 1) * 16384;
        const _Float16* bufB = bufA + 8192;
        #pragma unroll
        for (int ks = 0; ks < 2; ++ks) {
            const int sl = (ks << 2) | kc;
            half8 bf[4];
            #pragma unroll
            for (int n = 0; n < 4; ++n) {
                const int row = wc * 64 + n * 16 + fr;
                bf[n] = *(const half8*)(bufB + row * 64 + ((sl ^ (row & 7)) << 3));
            }
            #pragma unroll
            for (int m = 0; m < 4; ++m) {
                const int row = wr * 64 + m * 16 + fr;
                half8 af = *(const half8*)(bufA + row * 64 + ((sl ^ (row & 7)) << 3));
                #pragma unroll
                for (int n = 0; n < 4; ++n)
                    acc[m][n] = __builtin_amdgcn_mfma_f32_16x16x32_f16(af, bf[n], acc[m][n], 0, 0, 0);
            }
        }
        __syncthreads();   // drains prefetch (vmcnt 0) + releases buffers
    }

    float csum[4] = {0.f, 0.f, 0.f, 0.f};
    #pragma unroll
    for (int m = 0; m < 4; ++m) {
        const int gr0 = row0 + wr * 64 + m * 16 + kc * 4;
        #pragma unroll
        for (int n = 0; n < 4; ++n) {
            const int j = col0 + wc * 64 + n * 16 + fr;
            const float bj = bias[j];
            const int h = j >> 6, dd = j & 63;
            #pragma unroll
            for (int r2 = 0; r2 < 4; ++r2) {
                const int i = gr0 + r2;
                const int nn = i >> 11, l = i & (L_ - 1);
                float v = acc[m][n][r2] + bj;
                if (z < 2) { v = sigmoidf_(v); csum[n] += v; }
                outp[(((size_t)(nn * H_ + h)) * L_ + l) * HD_ + dd] = (_Float16)v;
            }
        }
    }

    if (z < 2) {
        float* scol = (float*)lds;             // LDS free after final barrier
        if (t < 128) scol[t] = 0.f;
        __syncthreads();
        #pragma unroll
        for (int n = 0; n < 4; ++n)
            atomicAdd(&scol[wc * 64 + n * 16 + fr], csum[n]);
        __syncthreads();
        if (t < 128) {
            const int j = col0 + t;
            const int nn = row0 >> 11;
            float* dst = (z == 0) ? qsum : ksum;
            atomicAdd(&dst[(nn * H_ + (j >> 6)) * 64 + (j & 63)], scol[t]);
        }
    }
}

// ===========================================================================
// Output GEMM: single-product f16, BK=64, 2-phase dbuf, XCD grid (512 = 8x64)
// ===========================================================================
__global__ __launch_bounds__(256) void gemm_out_kernel(
    const _Float16* __restrict__ af, const _Float16* __restrict__ wo,
    const float* __restrict__ bias, float* __restrict__ outp)
{
    const int bid = (int)blockIdx.x;
    const int wg = (bid & 7) * 64 + (bid >> 3);
    const int row0 = (wg >> 3) * 128;
    const int col0 = (wg & 7) * 128;

    __shared__ _Float16 lds[2 * 16384];
    const int t = threadIdx.x;
    const int lane = t & 63;
    const int w = t >> 6;
    const int wr = w >> 1, wc = w & 1;
    const int fr = lane & 15, kc = lane >> 4;

    auto STAGE = [&](int k0, int buf) {
        const _Float16* a_g = af + (size_t)row0 * DM + k0;
        const _Float16* b_g = wo + (size_t)col0 * DM + k0;
        _Float16* dst = lds + buf * 16384;
        #pragma unroll
        for (int p = 0; p < 4; ++p) {
            const int b = p * 4096 + t * 16;
            const int r = b >> 7;
            const int s = (b >> 4) & 7;
            const int c = ((s ^ (r & 7)) << 3);
            const size_t go = (size_t)r * DM + c;
            GLOAD16(a_g + go, dst + (b >> 1));
            GLOAD16(b_g + go, dst + 8192 + (b >> 1));
        }
    };

    f32x4 acc[4][4];
    #pragma unroll
    for (int m = 0; m < 4; ++m)
        #pragma unroll
        for (int n = 0; n < 4; ++n) acc[m][n] = f32x4{0.f, 0.f, 0.f, 0.f};

    STAGE(0, 0);
    __syncthreads();

    for (int kt = 0; kt < 16; ++kt) {
        if (kt + 1 < 16) STAGE((kt + 1) * 64, (kt + 1) & 1);
        const _Float16* bufA = lds + (kt & 1) * 16384;
        const _Float16* bufB = bufA + 8192;
        #pragma unroll
        for (int ks = 0; ks < 2; ++ks) {
            const int sl = (ks << 2) | kc;
            half8 bf[4];
            #pragma unroll
            for (int n = 0; n < 4; ++n) {
                const int row = wc * 64 + n * 16 + fr;
                bf[n] = *(const half8*)(bufB + row * 64 + ((sl ^ (row & 7)) << 3));
            }
            #pragma unroll
            for (int m = 0; m < 4; ++m) {
                const int row = wr * 64 + m * 16 + fr;
                half8 af8 = *(const half8*)(bufA + row * 64 + ((sl ^ (row & 7)) << 3));
                #pragma unroll
                for (int n = 0; n < 4; ++n)
                    acc[m][n] = __builtin_amdgcn_mfma_f32_16x16x32_f16(af8, bf[n], acc[m][n], 0, 0, 0);
            }
        }
        __syncthreads();
    }

    #pragma unroll
    for (int m = 0; m < 4; ++m) {
        const int gr0 = row0 + wr * 64 + m * 16 + kc * 4;
        #pragma unroll
        for (int n = 0; n < 4; ++n) {
            const int j = col0 + wc * 64 + n * 16 + fr;
            const float bj = bias[j];
            #pragma unroll
            for (int r2 = 0; r2 < 4; ++r2)
                outp[(size_t)(gr0 + r2) * DM + j] = acc[m][n][r2] + bj;
        }
    }
}

// ---------------------------------------------------------------------------
// stage1 — rowgroup-8 dots (proven R12)
// ---------------------------------------------------------------------------
__global__ __launch_bounds__(256) void stage1_kernel(
    const _Float16* __restrict__ q, const _Float16* __restrict__ k,
    const float* __restrict__ qsum, const float* __restrict__ ksum,
    float* __restrict__ si, float* __restrict__ qsi, float* __restrict__ kso)
{
    const int nh = blockIdx.x, ch = blockIdx.y;
    const _Float16* qp = q + (size_t)nh * L_ * HD_;
    const _Float16* kp = k + (size_t)nh * L_ * HD_;
    const int tid = threadIdx.x;
    const int lane = tid & 63;
    const int w = tid >> 6;
    const int r8 = lane >> 3;
    const int oct = lane & 7;

    __shared__ float ksum_s[64], qsum_s[64];
    __shared__ float s1[4][64], s2[4][64];
    if (tid < 64) {
        ksum_s[tid] = ksum[nh * 64 + tid] + EPS_;
        qsum_s[tid] = qsum[nh * 64 + tid] + EPS_;
    }
    __syncthreads();

    float qacc[8] = {0.f}, kacc[8] = {0.f};
    #pragma unroll
    for (int it = 0; it < 8; ++it) {
        const int l = ch * 256 + it * 32 + w * 8 + r8;
        half8 q8 = *(const half8*)(qp + (size_t)l * HD_ + oct * 8);
        half8 k8 = *(const half8*)(kp + (size_t)l * HD_ + oct * 8);
        float a = 0.f, b = 0.f;
        #pragma unroll
        for (int j = 0; j < 8; ++j) {
            a += ((float)q8[j] + EPS_) * ksum_s[oct * 8 + j];
            b += ((float)k8[j] + EPS_) * qsum_s[oct * 8 + j];
        }
        a += __shfl_xor(a, 1); a += __shfl_xor(a, 2); a += __shfl_xor(a, 4);
        b += __shfl_xor(b, 1); b += __shfl_xor(b, 2); b += __shfl_xor(b, 4);
        const float siv = 1.f / a;
        const float sov = 1.f / b;
        if (oct == 0) si[nh * L_ + l] = siv;
        #pragma unroll
        for (int j = 0; j < 8; ++j) {
            qacc[j] += (float)q8[j] * siv;
            kacc[j] += (float)k8[j] * sov;
        }
    }
    #pragma unroll
    for (int j = 0; j < 8; ++j) {
        qacc[j] += __shfl_xor(qacc[j], 8);  qacc[j] += __shfl_xor(qacc[j], 16); qacc[j] += __shfl_xor(qacc[j], 32);
        kacc[j] += __shfl_xor(kacc[j], 8);  kacc[j] += __shfl_xor(kacc[j], 16); kacc[j] += __shfl_xor(kacc[j], 32);
    }
    if (r8 == 0) {
        #pragma unroll
        for (int j = 0; j < 8; ++j) { s1[w][oct * 8 + j] = qacc[j]; s2[w][oct * 8 + j] = kacc[j]; }
    }
    __syncthreads();
    if (tid < 64) {
        atomicAdd(&qsi[nh * 64 + tid], s1[0][tid] + s1[1][tid] + s1[2][tid] + s1[3][tid]);
        atomicAdd(&kso[nh * 64 + tid], s2[0][tid] + s2[1][tid] + s2[2][tid] + s2[3][tid]);
    }
}

// ---------------------------------------------------------------------------
// kv partial with fused source-competition (rowgroup p-dots); results
// atomicAdd directly into kvb (zeroed in prep) — no reduce kernel.
// ---------------------------------------------------------------------------
__global__ __launch_bounds__(256) void kv_part_kernel(
    const _Float16* __restrict__ k, const _Float16* __restrict__ v,
    const float* __restrict__ qsi, float* __restrict__ kvb, float* __restrict__ psum_p)
{
    const int nh = blockIdx.x, ch = blockIdx.y;
    const _Float16* kp = k + (size_t)nh * L_ * HD_;
    const _Float16* vp = v + (size_t)nh * L_ * HD_;
    const int tid = threadIdx.x;
    const int lane = tid & 63;
    const int w = tid >> 6;
    const int row8 = tid >> 3;
    const int oct = tid & 7;

    __shared__ float qsi_s[64];
    __shared__ float ks[32][65], vs[32][65];
    __shared__ float pl[32];
    if (tid < 64) qsi_s[tid] = qsi[nh * 64 + tid] + EPS_;
    __syncthreads();

    float acc[16] = {0.f};
    float psum_acc = 0.f;
    for (int l0 = ch * 256; l0 < (ch + 1) * 256; l0 += 32) {
        {
            const half8* kp8 = (const half8*)(kp + (size_t)l0 * HD_);
            const half8* vp8 = (const half8*)(vp + (size_t)l0 * HD_);
            half8 k8 = kp8[tid];
            half8 v8 = vp8[tid];
            const int r = tid >> 3, c = (tid & 7) * 8;
            #pragma unroll
            for (int j = 0; j < 8; ++j) {
                ks[r][c + j] = (float)k8[j];
                vs[r][c + j] = (float)v8[j];
            }
        }
        __syncthreads();
        {
            float b = 0.f;
            #pragma unroll
            for (int j = 0; j < 8; ++j)
                b += (ks[row8][oct * 8 + j] + EPS_) * qsi_s[oct * 8 + j];
            b += __shfl_xor(b, 1); b += __shfl_xor(b, 2); b += __shfl_xor(b, 4);
            b = fminf(1.f, fmaxf(-1.f, b));
            const float p = expf(b);
            if (oct == 0) { pl[row8] = p; psum_acc += p; }
        }
        __syncthreads();
        #pragma unroll 4
        for (int ll = 0; ll < 32; ++ll) {
            const float vv = vs[ll][lane] * pl[ll];
            #pragma unroll
            for (int dd = 0; dd < 16; ++dd) acc[dd] += ks[ll][w * 16 + dd] * vv;
        }
        __syncthreads();
    }
    #pragma unroll
    for (int dd = 0; dd < 16; ++dd)
        atomicAdd(&kvb[(size_t)nh * 4096 + (w * 16 + dd) * 64 + lane], acc[dd]);

    psum_acc += __shfl_xor(psum_acc, 8);
    psum_acc += __shfl_xor(psum_acc, 16);
    psum_acc += __shfl_xor(psum_acc, 32);
    psum_acc += __shfl_xor(psum_acc, 1);
    psum_acc += __shfl_xor(psum_acc, 2);
    psum_acc += __shfl_xor(psum_acc, 4);
    __shared__ float sp[4];
    if (lane == 0) sp[w] = psum_acc;
    __syncthreads();
    if (tid == 0) psum_p[nh * 8 + ch] = sp[0] + sp[1] + sp[2] + sp[3];
}

// ---------------------------------------------------------------------------
// out with fused sink_allocation + deferred softmax scale; f16 attn store
// ---------------------------------------------------------------------------
__global__ __launch_bounds__(256) void out_kernel(
    const _Float16* __restrict__ q, const float* __restrict__ kvb,
    const float* __restrict__ si, const float* __restrict__ kso,
    const float* __restrict__ psum_p,
    _Float16* __restrict__ attn_f)
{
    const int nh = blockIdx.x;
    const int n = nh >> 4;
    const int h = nh & 15;
    const int l0 = blockIdx.y * 64;
    __shared__ float kvs[64][64];
    __shared__ float qs[64][65];
    __shared__ float sal[64];
    __shared__ float kso_s[64];
    const int tid = threadIdx.x;
    float tot = 0.f;
    #pragma unroll
    for (int c = 0; c < 8; ++c) tot += psum_p[nh * 8 + c];
    const float scale = (float)L_ / tot;
    for (int i = tid; i < 4096; i += 256)
        kvs[i >> 6][i & 63] = kvb[(size_t)nh * 4096 + i];
    {
        const half8* src8 = (const half8*)(q + ((size_t)nh * L_ + l0) * HD_);
        for (int i = tid; i < 512; i += 256) {
            half8 v8 = src8[i];
            const int r = i >> 3, c = (i & 7) * 8;
            #pragma unroll
            for (int j = 0; j < 8; ++j) qs[r][c + j] = (float)v8[j];
        }
    }
    if (tid < 64) kso_s[tid] = kso[nh * 64 + tid] + EPS_;
    __syncthreads();
    {
        const int row = tid >> 3;           // 0..31
        const int oct = tid & 7;
        #pragma unroll
        for (int rr = 0; rr < 2; ++rr) {
            const int r = rr * 32 + row;
            float a = 0.f;
            #pragma unroll
            for (int j = 0; j < 8; ++j)
                a += (qs[r][oct * 8 + j] + EPS_) * kso_s[oct * 8 + j];
            a += __shfl_xor(a, 1); a += __shfl_xor(a, 2); a += __shfl_xor(a, 4);
            if (oct == 0) sal[r] = sigmoidf_(a);
        }
    }
    __syncthreads();
    const int lane = tid & 63;
    const int w = tid >> 6;
    for (int ll = w; ll < 64; ll += 4) {
        const int l = l0 + ll;
        float acc = 0.f;
        #pragma unroll
        for (int d = 0; d < 64; ++d) acc += qs[ll][d] * kvs[d][lane];
        const float val = acc * si[nh * L_ + l] * sal[ll] * scale;
        attn_f[((size_t)n * L_ + l) * DM + h * 64 + lane] = (_Float16)val;
    }
}

extern "C" void kernel_launch(void* const* d_in, const int* in_sizes, int n_in,
                              void* d_out, int out_size, void* d_ws, size_t ws_size,
                              hipStream_t stream)
{
    const float* x  = (const float*)d_in[0];
    const float* Wq = (const float*)d_in[1];
    const float* bq = (const float*)d_in[2];
    const float* Wk = (const float*)d_in[3];
    const float* bk = (const float*)d_in[4];
    const float* Wv = (const float*)d_in[5];
    const float* bv = (const float*)d_in[6];
    const float* Wo = (const float*)d_in[7];
    const float* bo = (const float*)d_in[8];
    float* out = (float*)d_out;

    float* ws = (float*)d_ws;
    size_t off = 0;
    const size_t big = (size_t)B_ * L_ * DM;   // 8,388,608 elems
    _Float16* qbuf = (_Float16*)(ws + off); off += big / 2;
    _Float16* kbuf = (_Float16*)(ws + off); off += big / 2;
    _Float16* vbuf = (_Float16*)(ws + off); off += big / 2;
    _Float16* xf = (_Float16*)(ws + off);
    _Float16* attn_f = xf;
    off += big / 2;
    _Float16* wh3 = (_Float16*)(ws + off); off += (size_t)3 * DM * DM / 2;
    _Float16* woh = (_Float16*)(ws + off); off += (size_t)DM * DM / 2;
    float* kvb    = ws + off; off += (size_t)NH_ * 64 * 64;
    float* sums = ws + off;
    float* qsum = sums;
    float* ksum = sums + 1 * NH_ * 64;
    float* qsi  = sums + 2 * NH_ * 64;
    float* kso  = sums + 3 * NH_ * 64;
    off += 4 * NH_ * 64;
    float* psum_p = ws + off; off += NH_ * 8;
    float* si     = ws + off; off += NH_ * L_;

    // 1. prep: x -> f16, weights -> f16, zero kvb + accumulators (one launch)
    prep_kernel<<<12288, 256, 0, stream>>>(x, Wq, Wk, Wv, Wo, xf, wh3, woh, sums, kvb);

    // 2. QKV projection GEMMs (2-phase dbuf, single-product f16, XCD swizzle)
    gemm_qkv_kernel<<<1536, 256, 0, stream>>>(xf, wh3, bq, bk, bv,
                                              qbuf, kbuf, vbuf, qsum, ksum);

    // 3. stage1 (rowgroup dots; si + qsi/kso atomics)
    stage1_kernel<<<dim3(NH_, 8), 256, 0, stream>>>(qbuf, kbuf, qsum, ksum, si, qsi, kso);

    // 4. kv with fused source-competition -> atomicAdd into kvb
    kv_part_kernel<<<dim3(NH_, 8), 256, 0, stream>>>(kbuf, vbuf, qsi, kvb, psum_p);

    // 5. out with fused sink_allocation + softmax scale -> f16 attn
    out_kernel<<<dim3(NH_, L_ / 64), 256, 0, stream>>>(qbuf, kvb, si, kso, psum_p, attn_f);

    // 6. output projection GEMM (2-phase dbuf, single-product f16, XCD swizzle)
    gemm_out_kernel<<<512, 256, 0, stream>>>(attn_f, woh, bo, out);
}